// Round 5
// baseline (908.142 us; speedup 1.0000x reference)
//
#include <hip/hip_runtime.h>

// GATGuard: 2-layer GAT with cosine-similarity edge gating (att_coef).
// N=50000 nodes, E=800000 raw edges, H=4 heads, F=64 feat/head, HF=256.
// Outputs: h1 [N,256], att_w [E], self_w [N]  (concatenated in d_out).

#define NH 4
#define NF 64
#define HF 256

__device__ __forceinline__ float wred_sum(float v) {
#pragma unroll
  for (int o = 32; o > 0; o >>= 1) v += __shfl_xor(v, o, 64);
  return v;
}
__device__ __forceinline__ float lrelu(float x, float s) {
  return x > 0.f ? x : s * x;
}
__device__ __forceinline__ float bf2f(unsigned short u) {
  union { float f; unsigned int i; } v;
  v.i = ((unsigned int)u) << 16;
  return v.f;
}
__device__ __forceinline__ unsigned short f2bf(float f) {  // RNE
  union { float f; unsigned int i; } v;
  v.f = f;
  unsigned int r = v.i + 0x7fffu + ((v.i >> 16) & 1u);
  return (unsigned short)(r >> 16);
}
__device__ __forceinline__ float dot_bf16x8(uint4 a, uint4 b) {
  const unsigned int* pa = (const unsigned int*)&a;
  const unsigned int* pb = (const unsigned int*)&b;
  float acc = 0.f;
#pragma unroll
  for (int i = 0; i < 4; ++i) {
    acc += bf2f((unsigned short)(pa[i] & 0xffff)) *
           bf2f((unsigned short)(pb[i] & 0xffff));
    acc += bf2f((unsigned short)(pa[i] >> 16)) *
           bf2f((unsigned short)(pb[i] >> 16));
  }
  return acc;
}
__device__ __forceinline__ float4 unpack_bf4(uint2 q) {
  return make_float4(bf2f((unsigned short)(q.x & 0xffff)),
                     bf2f((unsigned short)(q.x >> 16)),
                     bf2f((unsigned short)(q.y & 0xffff)),
                     bf2f((unsigned short)(q.y >> 16)));
}

// ---- fused row-norm + normalized bf16 copy of x (wave per row, D=128) ----
__global__ __launch_bounds__(256) void xprep_kernel(
    const float* __restrict__ X, float* __restrict__ inv,
    unsigned short* __restrict__ xnb, int n) {
  int row = blockIdx.x * 4 + (threadIdx.x >> 6);
  int lane = threadIdx.x & 63;
  if (row >= n) return;
  float2 v = ((const float2*)(X + (size_t)row * 128))[lane];
  float acc = v.x * v.x + v.y * v.y;
  acc = wred_sum(acc);
  float s = 1.f / fmaxf(sqrtf(acc), 1e-12f);
  if (lane == 0) inv[row] = s;
  unsigned int packed =
      (unsigned int)f2bf(v.x * s) | ((unsigned int)f2bf(v.y * s) << 16);
  ((unsigned int*)(xnb + (size_t)row * 128))[lane] = packed;
}

// ---- layer-0 cosine mask + compaction (8-lane group per edge) -----------
// bf16 dot (256 B dst gather; src row L1-hot) + exact f32 recheck near 0.1.
// Survivors are compacted via block-level ballot + one atomic (order-free:
// downstream writes are keyed by original edge id).
__global__ __launch_bounds__(256) void edge_mask_compact_kernel(
    const unsigned short* __restrict__ xnb, const float* __restrict__ X,
    const float* __restrict__ xinv, const int* __restrict__ c2src,
    const int* __restrict__ c2dst, const int* __restrict__ c2eid,
    int* __restrict__ cs, int* __restrict__ cd, int* __restrict__ ce,
    int* __restrict__ cnt, int E_) {
  int p = blockIdx.x * 32 + (threadIdx.x >> 3);
  int gl = threadIdx.x & 7;
  int lane = threadIdx.x & 63;
  int wv = threadIdx.x >> 6;
  bool mk = false;
  int s = 0, d = 0;
  if (p < E_) {
    s = c2src[p];
    d = c2dst[p];
    const uint4* ps = (const uint4*)(xnb + (size_t)s * 128);
    const uint4* pd = (const uint4*)(xnb + (size_t)d * 128);
    uint4 a0 = ps[gl], a1 = ps[gl + 8];
    uint4 b0 = pd[gl], b1 = pd[gl + 8];
    float acc = dot_bf16x8(a0, b0) + dot_bf16x8(a1, b1);
#pragma unroll
    for (int o = 1; o < 8; o <<= 1) acc += __shfl_xor(acc, o, 64);
    if (fabsf(acc - 0.1f) < 4e-3f) {  // exact recheck (~2% of edges)
      const float4* fs = (const float4*)(X + (size_t)s * 128);
      const float4* fd = (const float4*)(X + (size_t)d * 128);
      float a2 = 0.f;
#pragma unroll
      for (int i = 0; i < 4; ++i) {
        float4 fa = fs[gl + 8 * i], fb = fd[gl + 8 * i];
        a2 += fa.x * fb.x + fa.y * fb.y + fa.z * fb.z + fa.w * fb.w;
      }
#pragma unroll
      for (int o = 1; o < 8; o <<= 1) a2 += __shfl_xor(a2, o, 64);
      mk = (a2 * xinv[s] * xinv[d]) >= 0.1f;
    } else {
      mk = acc >= 0.1f;
    }
  }
  // block compaction
  __shared__ int wbase[4];
  bool lead = (gl == 0) && mk;
  unsigned long long ball = __ballot(lead);
  if (lane == 0) wbase[wv] = __popcll(ball);
  __syncthreads();
  if (threadIdx.x == 0) {
    int tot = wbase[0] + wbase[1] + wbase[2] + wbase[3];
    int b = atomicAdd(cnt, tot);
    for (int i = 0; i < 4; ++i) {
      int c = wbase[i];
      wbase[i] = b;
      b += c;
    }
  }
  __syncthreads();
  if (lead) {
    int pos = wbase[wv] + __popcll(ball & ((1ull << lane) - 1ull));
    cs[pos] = s;
    cd[pos] = d;
    ce[pos] = c2eid[p];
  }
}

// ---- att_coef #2 over compacted survivors: 16-lane group per edge -------
__global__ __launch_bounds__(256) void sim2_kernel(
    const float* __restrict__ Hf, const float* __restrict__ hinv,
    const int* __restrict__ cs, const int* __restrict__ cd,
    const int* __restrict__ cnt, float* __restrict__ svc,
    float* __restrict__ rowsum, float* __restrict__ degf) {
  int S = cnt[0];
  int gl = threadIdx.x & 15;
  int g0 = blockIdx.x * 16 + (threadIdx.x >> 4);
  int gstride = gridDim.x * 16;
  for (int q = g0; q < S; q += gstride) {
    int s = cs[q], d = cd[q];
    const float4* hs = (const float4*)(Hf + (size_t)s * 256);
    const float4* hd = (const float4*)(Hf + (size_t)d * 256);
    float acc = 0.f;
#pragma unroll
    for (int i = 0; i < 4; ++i) {
      float4 a = hs[gl + 16 * i], b = hd[gl + 16 * i];
      acc += a.x * b.x + a.y * b.y + a.z * b.z + a.w * b.w;
    }
#pragma unroll
    for (int o = 1; o < 16; o <<= 1) acc += __shfl_xor(acc, o, 64);
    if (gl == 0) {
      float sim = acc * hinv[s] * hinv[d];
      float sv = (sim >= 0.1f) ? sim : 0.f;
      svc[q] = sv;
      if (sv > 0.f) {
        atomicAdd(&rowsum[s], sv);
        atomicAdd(&degf[s], 1.0f);
      }
    }
  }
}

// ---- att_w over survivors (out_att pre-zeroed) ---------------------------
__global__ __launch_bounds__(256) void att_w_kernel(
    const float* __restrict__ svc, const float* __restrict__ rowsum,
    const int* __restrict__ cs, const int* __restrict__ ce,
    const int* __restrict__ cnt, float* __restrict__ out_att) {
  int S = cnt[0];
  int stride = gridDim.x * blockDim.x;
  for (int q = blockIdx.x * blockDim.x + threadIdx.x; q < S; q += stride) {
    float sv = svc[q];
    if (sv > 0.f) out_att[ce[q]] = __expf(sv / rowsum[cs[q]]);
  }
}

// ---- self_w (thread per node) --------------------------------------------
__global__ __launch_bounds__(256) void self_w_kernel(
    const float* __restrict__ degf, float* __restrict__ out_self, int n) {
  int i = blockIdx.x * blockDim.x + threadIdx.x;
  if (i >= n) return;
  out_self[i] = __expf(1.f / (degf[i] + 1.f));
}

// ---- tiled FP32 GEMM + fused epilogue -----------------------------------
// C[n,M] = A[n,K] @ B[K,M]; 128x128 tile, 256 threads, 8x8 microtile.
// Epilogue: stores feat as bf16 (feat16) and computes el/er per (row,head)
// exactly from the f32 accumulators (16-lane shuffle reduction; each
// (row,head) owned by exactly one block -> plain stores, no atomics).
__global__ __launch_bounds__(256) void gemm_kernel(
    const float* __restrict__ A, const float* __restrict__ B,
    const float* __restrict__ Av, unsigned short* __restrict__ feat16,
    float* __restrict__ el, float* __restrict__ er, int n, int K, int M) {
  __shared__ float As[16][128];
  __shared__ float Bs[16][128];
  int tid = threadIdx.x;
  int tx = tid & 15, ty = tid >> 4;
  int row0 = blockIdx.x * 128;
  int col0 = blockIdx.y * 128;
  float acc[8][8] = {};
  for (int k0 = 0; k0 < K; k0 += 16) {
#pragma unroll
    for (int i = 0; i < 2; ++i) {
      int p = tid + i * 256;
      int r = p >> 2, c4 = p & 3;
      int gr = row0 + r;
      float4 v = make_float4(0.f, 0.f, 0.f, 0.f);
      if (gr < n) v = *(const float4*)(A + (size_t)gr * K + k0 + c4 * 4);
      As[c4 * 4 + 0][r] = v.x;
      As[c4 * 4 + 1][r] = v.y;
      As[c4 * 4 + 2][r] = v.z;
      As[c4 * 4 + 3][r] = v.w;
    }
#pragma unroll
    for (int i = 0; i < 2; ++i) {
      int p = tid + i * 256;
      int r = p >> 5, c4 = p & 31;
      *(float4*)&Bs[r][c4 * 4] =
          *(const float4*)(B + (size_t)(k0 + r) * M + col0 + c4 * 4);
    }
    __syncthreads();
#pragma unroll
    for (int k = 0; k < 16; ++k) {
      float4 a0v = *(const float4*)&As[k][ty * 4];
      float4 a1v = *(const float4*)&As[k][64 + ty * 4];
      float4 b0v = *(const float4*)&Bs[k][tx * 4];
      float4 b1v = *(const float4*)&Bs[k][64 + tx * 4];
      float av[8] = {a0v.x, a0v.y, a0v.z, a0v.w, a1v.x, a1v.y, a1v.z, a1v.w};
      float bv[8] = {b0v.x, b0v.y, b0v.z, b0v.w, b1v.x, b1v.y, b1v.z, b1v.w};
#pragma unroll
      for (int i = 0; i < 8; ++i)
#pragma unroll
        for (int j = 0; j < 8; ++j) acc[i][j] += av[i] * bv[j];
    }
    __syncthreads();
  }
  // attention-vector coefficients for this thread's 8 columns
  int hA = col0 >> 6;  // head of first 64-col half (even); second half = hA+1
  float aEl0[4], aEl1[4], aEr0[4], aEr1[4];
#pragma unroll
  for (int j = 0; j < 4; ++j) {
    aEl0[j] = Av[hA * 64 + tx * 4 + j];
    aEl1[j] = Av[(hA + 1) * 64 + tx * 4 + j];
    aEr0[j] = Av[HF + hA * 64 + tx * 4 + j];
    aEr1[j] = Av[HF + (hA + 1) * 64 + tx * 4 + j];
  }
#pragma unroll
  for (int half = 0; half < 2; ++half) {
#pragma unroll
    for (int i = 0; i < 4; ++i) {
      int gr = row0 + half * 64 + ty * 4 + i;
      int ai = half * 4 + i;
      // el/er partials (all lanes participate in the reduction)
      float pl0 = 0.f, pl1 = 0.f, pr0 = 0.f, pr1 = 0.f;
#pragma unroll
      for (int j = 0; j < 4; ++j) {
        pl0 += acc[ai][j] * aEl0[j];
        pl1 += acc[ai][4 + j] * aEl1[j];
        pr0 += acc[ai][j] * aEr0[j];
        pr1 += acc[ai][4 + j] * aEr1[j];
      }
#pragma unroll
      for (int o = 1; o < 16; o <<= 1) {
        pl0 += __shfl_xor(pl0, o, 64);
        pl1 += __shfl_xor(pl1, o, 64);
        pr0 += __shfl_xor(pr0, o, 64);
        pr1 += __shfl_xor(pr1, o, 64);
      }
      if (gr < n) {
        unsigned short* rp = feat16 + (size_t)gr * HF;
        unsigned int p0 = (unsigned int)f2bf(acc[ai][0]) |
                          ((unsigned int)f2bf(acc[ai][1]) << 16);
        unsigned int p1 = (unsigned int)f2bf(acc[ai][2]) |
                          ((unsigned int)f2bf(acc[ai][3]) << 16);
        ((uint2*)(rp + col0 + tx * 4))[0] = make_uint2(p0, p1);
        unsigned int p2 = (unsigned int)f2bf(acc[ai][4]) |
                          ((unsigned int)f2bf(acc[ai][5]) << 16);
        unsigned int p3 = (unsigned int)f2bf(acc[ai][6]) |
                          ((unsigned int)f2bf(acc[ai][7]) << 16);
        ((uint2*)(rp + col0 + 64 + tx * 4))[0] = make_uint2(p2, p3);
        if (tx == 0) {
          ((float2*)(el + gr * NH + hA))[0] = make_float2(pl0, pl1);
          ((float2*)(er + gr * NH + hA))[0] = make_float2(pr0, pr1);
        }
      }
    }
  }
}

// ---------------- CSR build (both orderings in one pass) ------------------
__global__ __launch_bounds__(256) void hist2_kernel(
    const int* __restrict__ src, const int* __restrict__ dst,
    int* __restrict__ deg, int* __restrict__ deg2, int E_) {
  int e = blockIdx.x * blockDim.x + threadIdx.x;
  if (e >= E_) return;
  atomicAdd(&deg[dst[e]], 1);
  atomicAdd(&deg2[src[e]], 1);
}

// 3-phase scan; gridDim.y selects which (deg,rs,bsum) pair.
__global__ __launch_bounds__(1024) void scanA2_kernel(
    const int* __restrict__ d0, const int* __restrict__ d1,
    int* __restrict__ r0, int* __restrict__ r1, int* __restrict__ b0,
    int* __restrict__ b1, int n) {
  const int* deg = blockIdx.y ? d1 : d0;
  int* rs = blockIdx.y ? r1 : r0;
  int* bsum = blockIdx.y ? b1 : b0;
  __shared__ int temp[1024];
  int tid = threadIdx.x;
  int idx = blockIdx.x * 1024 + tid;
  int v = (idx < n) ? deg[idx] : 0;
  temp[tid] = v;
  __syncthreads();
  for (int off = 1; off < 1024; off <<= 1) {
    int t = (tid >= off) ? temp[tid - off] : 0;
    __syncthreads();
    temp[tid] += t;
    __syncthreads();
  }
  if (idx < n) rs[idx] = temp[tid] - v;  // block-local exclusive
  if (tid == 1023) bsum[blockIdx.x] = temp[1023];
}

__global__ __launch_bounds__(1024) void scanB2_kernel(int* __restrict__ b0,
                                                      int* __restrict__ b1,
                                                      int nb) {
  int* bsum = blockIdx.x ? b1 : b0;
  __shared__ int t[1024];
  int tid = threadIdx.x;
  int v = (tid < nb) ? bsum[tid] : 0;
  t[tid] = v;
  __syncthreads();
  for (int off = 1; off < 1024; off <<= 1) {
    int u = (tid >= off) ? t[tid - off] : 0;
    __syncthreads();
    t[tid] += u;
    __syncthreads();
  }
  if (tid < nb) bsum[tid] = t[tid] - v;  // exclusive
  if (tid == 0) bsum[nb] = t[1023];      // total
}

__global__ __launch_bounds__(256) void scanC2_kernel(
    int* __restrict__ r0, int* __restrict__ r1, const int* __restrict__ b0,
    const int* __restrict__ b1, int n, int nb) {
  int* rs = blockIdx.y ? r1 : r0;
  const int* bsum = blockIdx.y ? b1 : b0;
  int idx = blockIdx.x * blockDim.x + threadIdx.x;
  if (idx < n) rs[idx] += bsum[idx >> 10];
  else if (idx == n) rs[n] = bsum[nb];
}

// both scatters in one pass
__global__ __launch_bounds__(256) void scatter12_kernel(
    const int* __restrict__ src, const int* __restrict__ dst,
    const int* __restrict__ rs, int* __restrict__ cursor,
    int* __restrict__ csr_src, const int* __restrict__ rs2,
    int* __restrict__ cursor2, int* __restrict__ c2src,
    int* __restrict__ c2dst, int* __restrict__ c2eid, int E_) {
  int e = blockIdx.x * blockDim.x + threadIdx.x;
  if (e >= E_) return;
  int s = src[e], d = dst[e];
  int pos = rs[d] + atomicAdd(&cursor[d], 1);
  csr_src[pos] = s;
  int pos2 = rs2[s] + atomicAdd(&cursor2[s], 1);
  c2src[pos2] = s;
  c2dst[pos2] = d;
  c2eid[pos2] = e;
}

// ---------------- GAT aggregation (wave per node, bf16 gathers) ----------
// lane l: features 4l..4l+3 (uint2 = 4 bf16, 8 B/lane -> 512 B/row).
// 8 CSR indices prefetched per lane-group and shfl-broadcast so the 8 row
// gathers issue back-to-back. No segment-max (scores O(1); exp safe).
__global__ __launch_bounds__(256) void gat_agg_kernel(
    const unsigned short* __restrict__ feat16, const float* __restrict__ el,
    const float* __restrict__ er, const int* __restrict__ row_start,
    const int* __restrict__ csr_src, const float* __restrict__ bias,
    float* __restrict__ out, float* __restrict__ inv_out, int n, int act) {
  int node = blockIdx.x * 4 + (threadIdx.x >> 6);
  int lane = threadIdx.x & 63;
  if (node >= n) return;
  int h = lane >> 4;
  const uint2* f16 = (const uint2*)feat16;
  float er_n = er[node * NH + h];
  float es = lrelu(el[node * NH + h] + er_n, 0.2f);
  int start = row_start[node];
  int deg = row_start[node + 1] - start;
  float ws = __expf(es);
  float4 fv = unpack_bf4(f16[(size_t)node * 64 + lane]);
  float4 facc = make_float4(ws * fv.x, ws * fv.y, ws * fv.z, ws * fv.w);
  float z = ws;
  for (int c = 0; c < deg; c += 8) {
    int t = c + (lane & 7);
    int myidx = (t < deg) ? csr_src[start + t] : 0;
    if (deg - c >= 8) {
#pragma unroll
      for (int j = 0; j < 8; ++j) {
        int s = __shfl(myidx, j, 8);
        float w = __expf(lrelu(el[s * NH + h] + er_n, 0.2f));
        float4 f = unpack_bf4(f16[(size_t)s * 64 + lane]);
        facc.x += w * f.x;
        facc.y += w * f.y;
        facc.z += w * f.z;
        facc.w += w * f.w;
        z += w;
      }
    } else {
      int m8 = deg - c;
      for (int j = 0; j < m8; ++j) {
        int s = __shfl(myidx, j, 8);
        float w = __expf(lrelu(el[s * NH + h] + er_n, 0.2f));
        float4 f = unpack_bf4(f16[(size_t)s * 64 + lane]);
        facc.x += w * f.x;
        facc.y += w * f.y;
        facc.z += w * f.z;
        facc.w += w * f.w;
        z += w;
      }
    }
  }
  float rz = 1.f / z;
  float4 bb = ((const float4*)bias)[lane];
  float4 o_;
  o_.x = facc.x * rz + bb.x;
  o_.y = facc.y * rz + bb.y;
  o_.z = facc.z * rz + bb.z;
  o_.w = facc.w * rz + bb.w;
  if (act) {
    o_.x = lrelu(o_.x, 0.01f);
    o_.y = lrelu(o_.y, 0.01f);
    o_.z = lrelu(o_.z, 0.01f);
    o_.w = lrelu(o_.w, 0.01f);
  }
  ((float4*)out)[(size_t)node * 64 + lane] = o_;
  if (inv_out) {  // fused row-norm for the next att_coef
    float sq = o_.x * o_.x + o_.y * o_.y + o_.z * o_.z + o_.w * o_.w;
    sq = wred_sum(sq);
    if (lane == 0) inv_out[node] = 1.f / fmaxf(sqrtf(sq), 1e-12f);
  }
}

extern "C" void kernel_launch(void* const* d_in, const int* in_sizes, int n_in,
                              void* d_out, int out_size, void* d_ws, size_t ws_size,
                              hipStream_t stream) {
  const float* x = (const float*)d_in[0];
  const int* esrc = (const int*)d_in[1];
  const int* edst = (const int*)d_in[2];
  const float* W0 = (const float*)d_in[3];
  const float* a0 = (const float*)d_in[4];
  const float* b0 = (const float*)d_in[5];
  const float* W1 = (const float*)d_in[6];
  const float* a1 = (const float*)d_in[7];
  const float* b1 = (const float*)d_in[8];

  const int N = in_sizes[0] / 128;  // 50000
  const int E = in_sizes[1];        // 800000

  // ---- workspace layout (256B aligned chunks) ----
  char* wp = (char*)d_ws;
  auto alloc = [&](size_t bytes) {
    char* p = wp;
    wp += (bytes + 255) & ~(size_t)255;
    return p;
  };
  float* h0 = (float*)alloc((size_t)N * HF * 4);
  unsigned short* feat16 = (unsigned short*)alloc((size_t)N * HF * 2);
  unsigned short* xnb = (unsigned short*)alloc((size_t)N * 128 * 2);
  float* xinv = (float*)alloc((size_t)N * 4);
  float* h0inv = (float*)alloc((size_t)N * 4);
  float* el = (float*)alloc((size_t)N * NH * 4);
  float* er = (float*)alloc((size_t)N * NH * 4);
  float* svc = (float*)alloc((size_t)E * 4);
  int* row_start = (int*)alloc((size_t)(N + 1) * 4);
  int* row_start2 = (int*)alloc((size_t)(N + 1) * 4);
  int* csr_src = (int*)alloc((size_t)E * 4);
  int* c2src = (int*)alloc((size_t)E * 4);
  int* c2dst = (int*)alloc((size_t)E * 4);
  int* c2eid = (int*)alloc((size_t)E * 4);
  int* cs = (int*)alloc((size_t)E * 4);
  int* cd = (int*)alloc((size_t)E * 4);
  int* ce = (int*)alloc((size_t)E * 4);
  const int NSB = (N + 1023) / 1024;  // node-scan blocks
  int* bsum = (int*)alloc((size_t)(NSB + 1) * 4);
  int* bsum2 = (int*)alloc((size_t)(NSB + 1) * 4);
  // contiguous zero region: deg_i, cursor, deg2_i, cursor2, rowsum, degf, cnt
  char* zero_base = wp;
  int* deg_i = (int*)alloc((size_t)N * 4);
  int* cursor = (int*)alloc((size_t)N * 4);
  int* deg2_i = (int*)alloc((size_t)N * 4);
  int* cursor2 = (int*)alloc((size_t)N * 4);
  float* rowsum = (float*)alloc((size_t)N * 4);
  float* degf = (float*)alloc((size_t)N * 4);
  int* cnt = (int*)alloc(4);
  size_t zero_bytes = (size_t)(wp - zero_base);

  float* out_h = (float*)d_out;            // [N,256]
  float* out_att = out_h + (size_t)N * HF; // [E]
  float* out_self = out_att + E;           // [N]

  const int NB4 = (N + 3) / 4;        // wave-per-node grids
  const int EBT = (E + 255) / 256;    // thread-per-edge grids
  const int NBT = (N + 255) / 256;
  const int EB8 = (E + 31) / 32;      // 8-lane-group-per-edge grid

  // ---- zero accumulators (ws/d_out are poisoned before every call) ----
  hipMemsetAsync(zero_base, 0, zero_bytes, stream);
  hipMemsetAsync(out_att, 0, (size_t)E * 4, stream);

  // ---- CSR by dst (gat_agg) and by src (att_coef), fused passes ----
  hist2_kernel<<<EBT, 256, 0, stream>>>(esrc, edst, deg_i, deg2_i, E);
  {
    dim3 ga(NSB, 2);
    scanA2_kernel<<<ga, 1024, 0, stream>>>(deg_i, deg2_i, row_start,
                                           row_start2, bsum, bsum2, N);
    scanB2_kernel<<<2, 1024, 0, stream>>>(bsum, bsum2, NSB);
    dim3 gc((N + 256) / 256, 2);
    scanC2_kernel<<<gc, 256, 0, stream>>>(row_start, row_start2, bsum, bsum2,
                                          N, NSB);
  }
  scatter12_kernel<<<EBT, 256, 0, stream>>>(esrc, edst, row_start, cursor,
                                            csr_src, row_start2, cursor2,
                                            c2src, c2dst, c2eid, E);

  // ---- att_coef #1 on x: bf16 cosine mask + survivor compaction ----
  xprep_kernel<<<NB4, 256, 0, stream>>>(x, xinv, xnb, N);
  edge_mask_compact_kernel<<<EB8, 256, 0, stream>>>(
      xnb, x, xinv, c2src, c2dst, c2eid, cs, cd, ce, cnt, E);

  // ---- layer 0: feat16/el/er = fused gemm; aggregate -> h0 ----
  {
    dim3 g((N + 127) / 128, HF / 128);
    gemm_kernel<<<g, 256, 0, stream>>>(x, W0, a0, feat16, el, er, N, 128, HF);
  }
  gat_agg_kernel<<<NB4, 256, 0, stream>>>(feat16, el, er, row_start, csr_src,
                                          b0, h0, h0inv, N, 1);

  // ---- att_coef #2 on h0 over survivors: att_w + self_w ----
  sim2_kernel<<<1024, 256, 0, stream>>>(h0, h0inv, cs, cd, cnt, svc, rowsum,
                                        degf);
  att_w_kernel<<<512, 256, 0, stream>>>(svc, rowsum, cs, ce, cnt, out_att);
  self_w_kernel<<<NBT, 256, 0, stream>>>(degf, out_self, N);

  // ---- layer 1: feat16/el/er = fused gemm; aggregate -> out_h ----
  {
    dim3 g((N + 127) / 128, HF / 128);
    gemm_kernel<<<g, 256, 0, stream>>>(h0, W1, a1, feat16, el, er, N, 256, HF);
  }
  gat_agg_kernel<<<NB4, 256, 0, stream>>>(feat16, el, er, row_start, csr_src,
                                          b1, out_h, nullptr, N, 0);
}

// Round 6
// 663.246 us; speedup vs baseline: 1.3692x; 1.3692x over previous
//
#include <hip/hip_runtime.h>

// GATGuard: 2-layer GAT with cosine-similarity edge gating (att_coef).
// N=50000 nodes, E=800000 raw edges, H=4 heads, F=64 feat/head, HF=256.
// Outputs: h1 [N,256], att_w [E], self_w [N]  (concatenated in d_out).

#define NH 4
#define NF 64
#define HF 256

__device__ __forceinline__ float wred_sum(float v) {
#pragma unroll
  for (int o = 32; o > 0; o >>= 1) v += __shfl_xor(v, o, 64);
  return v;
}
__device__ __forceinline__ float lrelu(float x, float s) {
  return x > 0.f ? x : s * x;
}
__device__ __forceinline__ float bf2f(unsigned short u) {
  union { float f; unsigned int i; } v;
  v.i = ((unsigned int)u) << 16;
  return v.f;
}
__device__ __forceinline__ unsigned short f2bf(float f) {  // RNE
  union { float f; unsigned int i; } v;
  v.f = f;
  unsigned int r = v.i + 0x7fffu + ((v.i >> 16) & 1u);
  return (unsigned short)(r >> 16);
}
__device__ __forceinline__ float dot_bf16x8(uint4 a, uint4 b) {
  const unsigned int* pa = (const unsigned int*)&a;
  const unsigned int* pb = (const unsigned int*)&b;
  float acc = 0.f;
#pragma unroll
  for (int i = 0; i < 4; ++i) {
    acc += bf2f((unsigned short)(pa[i] & 0xffff)) *
           bf2f((unsigned short)(pb[i] & 0xffff));
    acc += bf2f((unsigned short)(pa[i] >> 16)) *
           bf2f((unsigned short)(pb[i] >> 16));
  }
  return acc;
}
__device__ __forceinline__ float4 unpack_bf4(uint2 q) {
  return make_float4(bf2f((unsigned short)(q.x & 0xffff)),
                     bf2f((unsigned short)(q.x >> 16)),
                     bf2f((unsigned short)(q.y & 0xffff)),
                     bf2f((unsigned short)(q.y >> 16)));
}

// ---- fused row-norm + normalized bf16 copy of x (wave per row, D=128) ----
__global__ __launch_bounds__(256) void xprep_kernel(
    const float* __restrict__ X, float* __restrict__ inv,
    unsigned short* __restrict__ xnb, int n) {
  int row = blockIdx.x * 4 + (threadIdx.x >> 6);
  int lane = threadIdx.x & 63;
  if (row >= n) return;
  float2 v = ((const float2*)(X + (size_t)row * 128))[lane];
  float acc = v.x * v.x + v.y * v.y;
  acc = wred_sum(acc);
  float s = 1.f / fmaxf(sqrtf(acc), 1e-12f);
  if (lane == 0) inv[row] = s;
  unsigned int packed =
      (unsigned int)f2bf(v.x * s) | ((unsigned int)f2bf(v.y * s) << 16);
  ((unsigned int*)(xnb + (size_t)row * 128))[lane] = packed;
}

// ---- layer-0 cosine mask: 8-lane group per edge, CSR-by-src order --------
// bf16 dot (256 B dst gather; src row L1-hot) + exact f32 recheck near 0.1.
// No cross-block atomics (round-5's single-counter compaction was a 295 us
// contended-RMW conga); survivors compacted by the scan chain below.
__global__ __launch_bounds__(256) void edge_mask8_kernel(
    const unsigned short* __restrict__ xnb, const float* __restrict__ X,
    const float* __restrict__ xinv, const int* __restrict__ c2src,
    const int* __restrict__ c2dst, int* __restrict__ mask2, int E_) {
  int p = blockIdx.x * 32 + (threadIdx.x >> 3);
  int gl = threadIdx.x & 7;
  if (p >= E_) return;
  int s = c2src[p], d = c2dst[p];
  const uint4* ps = (const uint4*)(xnb + (size_t)s * 128);
  const uint4* pd = (const uint4*)(xnb + (size_t)d * 128);
  uint4 a0 = ps[gl], a1 = ps[gl + 8];
  uint4 b0 = pd[gl], b1 = pd[gl + 8];
  float acc = dot_bf16x8(a0, b0) + dot_bf16x8(a1, b1);
#pragma unroll
  for (int o = 1; o < 8; o <<= 1) acc += __shfl_xor(acc, o, 64);
  bool mk;
  if (fabsf(acc - 0.1f) < 4e-3f) {  // exact recheck (~2% of edges)
    const float4* fs = (const float4*)(X + (size_t)s * 128);
    const float4* fd = (const float4*)(X + (size_t)d * 128);
    float a2 = 0.f;
#pragma unroll
    for (int i = 0; i < 4; ++i) {
      float4 fa = fs[gl + 8 * i], fb = fd[gl + 8 * i];
      a2 += fa.x * fb.x + fa.y * fb.y + fa.z * fb.z + fa.w * fb.w;
    }
#pragma unroll
    for (int o = 1; o < 8; o <<= 1) a2 += __shfl_xor(a2, o, 64);
    mk = (a2 * xinv[s] * xinv[d]) >= 0.1f;
  } else {
    mk = acc >= 0.1f;
  }
  if (gl == 0) mask2[p] = mk ? 1 : 0;
}

// ---- compact surviving edges (deterministic via prefix scan) ------------
__global__ __launch_bounds__(256) void compact_kernel(
    const int* __restrict__ mask2, const int* __restrict__ pos2,
    const int* __restrict__ c2src, const int* __restrict__ c2dst,
    const int* __restrict__ c2eid, int* __restrict__ cs, int* __restrict__ cd,
    int* __restrict__ ce, int E_) {
  int p = blockIdx.x * blockDim.x + threadIdx.x;
  if (p >= E_) return;
  if (mask2[p]) {
    int q = pos2[p];
    cs[q] = c2src[p];
    cd[q] = c2dst[p];
    ce[q] = c2eid[p];
  }
}

// ---- att_coef #2 over compacted survivors: 16-lane group per edge -------
__global__ __launch_bounds__(256) void sim2_kernel(
    const float* __restrict__ Hf, const float* __restrict__ hinv,
    const int* __restrict__ cs, const int* __restrict__ cd,
    const int* __restrict__ total, float* __restrict__ svc,
    float* __restrict__ rowsum, float* __restrict__ degf) {
  int S = total[0];
  int gl = threadIdx.x & 15;
  int g0 = blockIdx.x * 16 + (threadIdx.x >> 4);
  int gstride = gridDim.x * 16;
  for (int q = g0; q < S; q += gstride) {
    int s = cs[q], d = cd[q];
    const float4* hs = (const float4*)(Hf + (size_t)s * 256);
    const float4* hd = (const float4*)(Hf + (size_t)d * 256);
    float acc = 0.f;
#pragma unroll
    for (int i = 0; i < 4; ++i) {
      float4 a = hs[gl + 16 * i], b = hd[gl + 16 * i];
      acc += a.x * b.x + a.y * b.y + a.z * b.z + a.w * b.w;
    }
#pragma unroll
    for (int o = 1; o < 16; o <<= 1) acc += __shfl_xor(acc, o, 64);
    if (gl == 0) {
      float sim = acc * hinv[s] * hinv[d];
      float sv = (sim >= 0.1f) ? sim : 0.f;
      svc[q] = sv;
      if (sv > 0.f) {
        atomicAdd(&rowsum[s], sv);
        atomicAdd(&degf[s], 1.0f);
      }
    }
  }
}

// ---- att_w over survivors (out_att pre-zeroed) ---------------------------
__global__ __launch_bounds__(256) void att_w_kernel(
    const float* __restrict__ svc, const float* __restrict__ rowsum,
    const int* __restrict__ cs, const int* __restrict__ ce,
    const int* __restrict__ total, float* __restrict__ out_att) {
  int S = total[0];
  int stride = gridDim.x * blockDim.x;
  for (int q = blockIdx.x * blockDim.x + threadIdx.x; q < S; q += stride) {
    float sv = svc[q];
    if (sv > 0.f) out_att[ce[q]] = __expf(sv / rowsum[cs[q]]);
  }
}

// ---- self_w (thread per node) --------------------------------------------
__global__ __launch_bounds__(256) void self_w_kernel(
    const float* __restrict__ degf, float* __restrict__ out_self, int n) {
  int i = blockIdx.x * blockDim.x + threadIdx.x;
  if (i >= n) return;
  out_self[i] = __expf(1.f / (degf[i] + 1.f));
}

// ---- tiled FP32 GEMM + fused epilogue -----------------------------------
// C[n,M] = A[n,K] @ B[K,M]; 128x128 tile, 256 threads, 8x8 microtile.
// Epilogue: stores feat as bf16 (feat16) and computes el/er per (row,head)
// exactly from the f32 accumulators (16-lane shuffle reduction; each
// (row,head) owned by exactly one block -> plain stores, no atomics).
__global__ __launch_bounds__(256) void gemm_kernel(
    const float* __restrict__ A, const float* __restrict__ B,
    const float* __restrict__ Av, unsigned short* __restrict__ feat16,
    float* __restrict__ el, float* __restrict__ er, int n, int K, int M) {
  __shared__ float As[16][128];
  __shared__ float Bs[16][128];
  int tid = threadIdx.x;
  int tx = tid & 15, ty = tid >> 4;
  int row0 = blockIdx.x * 128;
  int col0 = blockIdx.y * 128;
  float acc[8][8] = {};
  for (int k0 = 0; k0 < K; k0 += 16) {
#pragma unroll
    for (int i = 0; i < 2; ++i) {
      int p = tid + i * 256;
      int r = p >> 2, c4 = p & 3;
      int gr = row0 + r;
      float4 v = make_float4(0.f, 0.f, 0.f, 0.f);
      if (gr < n) v = *(const float4*)(A + (size_t)gr * K + k0 + c4 * 4);
      As[c4 * 4 + 0][r] = v.x;
      As[c4 * 4 + 1][r] = v.y;
      As[c4 * 4 + 2][r] = v.z;
      As[c4 * 4 + 3][r] = v.w;
    }
#pragma unroll
    for (int i = 0; i < 2; ++i) {
      int p = tid + i * 256;
      int r = p >> 5, c4 = p & 31;
      *(float4*)&Bs[r][c4 * 4] =
          *(const float4*)(B + (size_t)(k0 + r) * M + col0 + c4 * 4);
    }
    __syncthreads();
#pragma unroll
    for (int k = 0; k < 16; ++k) {
      float4 a0v = *(const float4*)&As[k][ty * 4];
      float4 a1v = *(const float4*)&As[k][64 + ty * 4];
      float4 b0v = *(const float4*)&Bs[k][tx * 4];
      float4 b1v = *(const float4*)&Bs[k][64 + tx * 4];
      float av[8] = {a0v.x, a0v.y, a0v.z, a0v.w, a1v.x, a1v.y, a1v.z, a1v.w};
      float bv[8] = {b0v.x, b0v.y, b0v.z, b0v.w, b1v.x, b1v.y, b1v.z, b1v.w};
#pragma unroll
      for (int i = 0; i < 8; ++i)
#pragma unroll
        for (int j = 0; j < 8; ++j) acc[i][j] += av[i] * bv[j];
    }
    __syncthreads();
  }
  // attention-vector coefficients for this thread's 8 columns
  int hA = col0 >> 6;  // head of first 64-col half (even); second half = hA+1
  float aEl0[4], aEl1[4], aEr0[4], aEr1[4];
#pragma unroll
  for (int j = 0; j < 4; ++j) {
    aEl0[j] = Av[hA * 64 + tx * 4 + j];
    aEl1[j] = Av[(hA + 1) * 64 + tx * 4 + j];
    aEr0[j] = Av[HF + hA * 64 + tx * 4 + j];
    aEr1[j] = Av[HF + (hA + 1) * 64 + tx * 4 + j];
  }
#pragma unroll
  for (int half = 0; half < 2; ++half) {
#pragma unroll
    for (int i = 0; i < 4; ++i) {
      int gr = row0 + half * 64 + ty * 4 + i;
      int ai = half * 4 + i;
      // el/er partials (all lanes participate in the reduction)
      float pl0 = 0.f, pl1 = 0.f, pr0 = 0.f, pr1 = 0.f;
#pragma unroll
      for (int j = 0; j < 4; ++j) {
        pl0 += acc[ai][j] * aEl0[j];
        pl1 += acc[ai][4 + j] * aEl1[j];
        pr0 += acc[ai][j] * aEr0[j];
        pr1 += acc[ai][4 + j] * aEr1[j];
      }
#pragma unroll
      for (int o = 1; o < 16; o <<= 1) {
        pl0 += __shfl_xor(pl0, o, 64);
        pl1 += __shfl_xor(pl1, o, 64);
        pr0 += __shfl_xor(pr0, o, 64);
        pr1 += __shfl_xor(pr1, o, 64);
      }
      if (gr < n) {
        unsigned short* rp = feat16 + (size_t)gr * HF;
        unsigned int p0 = (unsigned int)f2bf(acc[ai][0]) |
                          ((unsigned int)f2bf(acc[ai][1]) << 16);
        unsigned int p1 = (unsigned int)f2bf(acc[ai][2]) |
                          ((unsigned int)f2bf(acc[ai][3]) << 16);
        ((uint2*)(rp + col0 + tx * 4))[0] = make_uint2(p0, p1);
        unsigned int p2 = (unsigned int)f2bf(acc[ai][4]) |
                          ((unsigned int)f2bf(acc[ai][5]) << 16);
        unsigned int p3 = (unsigned int)f2bf(acc[ai][6]) |
                          ((unsigned int)f2bf(acc[ai][7]) << 16);
        ((uint2*)(rp + col0 + 64 + tx * 4))[0] = make_uint2(p2, p3);
        if (tx == 0) {
          ((float2*)(el + gr * NH + hA))[0] = make_float2(pl0, pl1);
          ((float2*)(er + gr * NH + hA))[0] = make_float2(pr0, pr1);
        }
      }
    }
  }
}

// ---------------- CSR build (both orderings in one pass) ------------------
__global__ __launch_bounds__(256) void hist2_kernel(
    const int* __restrict__ src, const int* __restrict__ dst,
    int* __restrict__ deg, int* __restrict__ deg2, int E_) {
  int e = blockIdx.x * blockDim.x + threadIdx.x;
  if (e >= E_) return;
  atomicAdd(&deg[dst[e]], 1);
  atomicAdd(&deg2[src[e]], 1);
}

// 3-phase scan; gridDim.y selects which (deg,rs,bsum) pair.
__global__ __launch_bounds__(1024) void scanA2_kernel(
    const int* __restrict__ d0, const int* __restrict__ d1,
    int* __restrict__ r0, int* __restrict__ r1, int* __restrict__ b0,
    int* __restrict__ b1, int n) {
  const int* deg = blockIdx.y ? d1 : d0;
  int* rs = blockIdx.y ? r1 : r0;
  int* bsum = blockIdx.y ? b1 : b0;
  __shared__ int temp[1024];
  int tid = threadIdx.x;
  int idx = blockIdx.x * 1024 + tid;
  int v = (idx < n) ? deg[idx] : 0;
  temp[tid] = v;
  __syncthreads();
  for (int off = 1; off < 1024; off <<= 1) {
    int t = (tid >= off) ? temp[tid - off] : 0;
    __syncthreads();
    temp[tid] += t;
    __syncthreads();
  }
  if (idx < n) rs[idx] = temp[tid] - v;  // block-local exclusive
  if (tid == 1023) bsum[blockIdx.x] = temp[1023];
}

__global__ __launch_bounds__(1024) void scanB2_kernel(int* __restrict__ b0,
                                                      int* __restrict__ b1,
                                                      int nb) {
  int* bsum = blockIdx.x ? b1 : b0;
  __shared__ int t[1024];
  int tid = threadIdx.x;
  int v = (tid < nb) ? bsum[tid] : 0;
  t[tid] = v;
  __syncthreads();
  for (int off = 1; off < 1024; off <<= 1) {
    int u = (tid >= off) ? t[tid - off] : 0;
    __syncthreads();
    t[tid] += u;
    __syncthreads();
  }
  if (tid < nb) bsum[tid] = t[tid] - v;  // exclusive
  if (tid == 0) bsum[nb] = t[1023];      // total
}

__global__ __launch_bounds__(256) void scanC2_kernel(
    int* __restrict__ r0, int* __restrict__ r1, const int* __restrict__ b0,
    const int* __restrict__ b1, int n, int nb) {
  int* rs = blockIdx.y ? r1 : r0;
  const int* bsum = blockIdx.y ? b1 : b0;
  int idx = blockIdx.x * blockDim.x + threadIdx.x;
  if (idx < n) rs[idx] += bsum[idx >> 10];
  else if (idx == n) rs[n] = bsum[nb];
}

// single-stream 3-phase scan (for the edge-mask compaction)
__global__ __launch_bounds__(1024) void scanA_kernel(
    const int* __restrict__ deg, int* __restrict__ rs, int* __restrict__ bsum,
    int n) {
  __shared__ int temp[1024];
  int tid = threadIdx.x;
  int idx = blockIdx.x * 1024 + tid;
  int v = (idx < n) ? deg[idx] : 0;
  temp[tid] = v;
  __syncthreads();
  for (int off = 1; off < 1024; off <<= 1) {
    int t = (tid >= off) ? temp[tid - off] : 0;
    __syncthreads();
    temp[tid] += t;
    __syncthreads();
  }
  if (idx < n) rs[idx] = temp[tid] - v;  // block-local exclusive
  if (tid == 1023) bsum[blockIdx.x] = temp[1023];
}

__global__ __launch_bounds__(1024) void scanB_kernel(int* __restrict__ bsum,
                                                     int nb) {
  __shared__ int t[1024];
  int tid = threadIdx.x;
  int v = (tid < nb) ? bsum[tid] : 0;
  t[tid] = v;
  __syncthreads();
  for (int off = 1; off < 1024; off <<= 1) {
    int u = (tid >= off) ? t[tid - off] : 0;
    __syncthreads();
    t[tid] += u;
    __syncthreads();
  }
  if (tid < nb) bsum[tid] = t[tid] - v;  // exclusive
  if (tid == 0) bsum[nb] = t[1023];      // total
}

__global__ __launch_bounds__(256) void scanC_kernel(
    int* __restrict__ rs, const int* __restrict__ bsum, int n, int nb) {
  int idx = blockIdx.x * blockDim.x + threadIdx.x;
  if (idx < n) rs[idx] += bsum[idx >> 10];
  else if (idx == n) rs[n] = bsum[nb];
}

// both scatters in one pass
__global__ __launch_bounds__(256) void scatter12_kernel(
    const int* __restrict__ src, const int* __restrict__ dst,
    const int* __restrict__ rs, int* __restrict__ cursor,
    int* __restrict__ csr_src, const int* __restrict__ rs2,
    int* __restrict__ cursor2, int* __restrict__ c2src,
    int* __restrict__ c2dst, int* __restrict__ c2eid, int E_) {
  int e = blockIdx.x * blockDim.x + threadIdx.x;
  if (e >= E_) return;
  int s = src[e], d = dst[e];
  int pos = rs[d] + atomicAdd(&cursor[d], 1);
  csr_src[pos] = s;
  int pos2 = rs2[s] + atomicAdd(&cursor2[s], 1);
  c2src[pos2] = s;
  c2dst[pos2] = d;
  c2eid[pos2] = e;
}

// ---------------- GAT aggregation (wave per node, bf16 gathers) ----------
// lane l: features 4l..4l+3 (uint2 = 4 bf16, 8 B/lane -> 512 B/row).
// 8 CSR indices prefetched per lane-group and shfl-broadcast so the 8 row
// gathers issue back-to-back. No segment-max (scores O(1); exp safe).
__global__ __launch_bounds__(256) void gat_agg_kernel(
    const unsigned short* __restrict__ feat16, const float* __restrict__ el,
    const float* __restrict__ er, const int* __restrict__ row_start,
    const int* __restrict__ csr_src, const float* __restrict__ bias,
    float* __restrict__ out, float* __restrict__ inv_out, int n, int act) {
  int node = blockIdx.x * 4 + (threadIdx.x >> 6);
  int lane = threadIdx.x & 63;
  if (node >= n) return;
  int h = lane >> 4;
  const uint2* f16 = (const uint2*)feat16;
  float er_n = er[node * NH + h];
  float es = lrelu(el[node * NH + h] + er_n, 0.2f);
  int start = row_start[node];
  int deg = row_start[node + 1] - start;
  float ws = __expf(es);
  float4 fv = unpack_bf4(f16[(size_t)node * 64 + lane]);
  float4 facc = make_float4(ws * fv.x, ws * fv.y, ws * fv.z, ws * fv.w);
  float z = ws;
  for (int c = 0; c < deg; c += 8) {
    int t = c + (lane & 7);
    int myidx = (t < deg) ? csr_src[start + t] : 0;
    if (deg - c >= 8) {
#pragma unroll
      for (int j = 0; j < 8; ++j) {
        int s = __shfl(myidx, j, 8);
        float w = __expf(lrelu(el[s * NH + h] + er_n, 0.2f));
        float4 f = unpack_bf4(f16[(size_t)s * 64 + lane]);
        facc.x += w * f.x;
        facc.y += w * f.y;
        facc.z += w * f.z;
        facc.w += w * f.w;
        z += w;
      }
    } else {
      int m8 = deg - c;
      for (int j = 0; j < m8; ++j) {
        int s = __shfl(myidx, j, 8);
        float w = __expf(lrelu(el[s * NH + h] + er_n, 0.2f));
        float4 f = unpack_bf4(f16[(size_t)s * 64 + lane]);
        facc.x += w * f.x;
        facc.y += w * f.y;
        facc.z += w * f.z;
        facc.w += w * f.w;
        z += w;
      }
    }
  }
  float rz = 1.f / z;
  float4 bb = ((const float4*)bias)[lane];
  float4 o_;
  o_.x = facc.x * rz + bb.x;
  o_.y = facc.y * rz + bb.y;
  o_.z = facc.z * rz + bb.z;
  o_.w = facc.w * rz + bb.w;
  if (act) {
    o_.x = lrelu(o_.x, 0.01f);
    o_.y = lrelu(o_.y, 0.01f);
    o_.z = lrelu(o_.z, 0.01f);
    o_.w = lrelu(o_.w, 0.01f);
  }
  ((float4*)out)[(size_t)node * 64 + lane] = o_;
  if (inv_out) {  // fused row-norm for the next att_coef
    float sq = o_.x * o_.x + o_.y * o_.y + o_.z * o_.z + o_.w * o_.w;
    sq = wred_sum(sq);
    if (lane == 0) inv_out[node] = 1.f / fmaxf(sqrtf(sq), 1e-12f);
  }
}

extern "C" void kernel_launch(void* const* d_in, const int* in_sizes, int n_in,
                              void* d_out, int out_size, void* d_ws, size_t ws_size,
                              hipStream_t stream) {
  const float* x = (const float*)d_in[0];
  const int* esrc = (const int*)d_in[1];
  const int* edst = (const int*)d_in[2];
  const float* W0 = (const float*)d_in[3];
  const float* a0 = (const float*)d_in[4];
  const float* b0 = (const float*)d_in[5];
  const float* W1 = (const float*)d_in[6];
  const float* a1 = (const float*)d_in[7];
  const float* b1 = (const float*)d_in[8];

  const int N = in_sizes[0] / 128;  // 50000
  const int E = in_sizes[1];        // 800000

  // ---- workspace layout (256B aligned chunks) ----
  char* wp = (char*)d_ws;
  auto alloc = [&](size_t bytes) {
    char* p = wp;
    wp += (bytes + 255) & ~(size_t)255;
    return p;
  };
  float* h0 = (float*)alloc((size_t)N * HF * 4);
  unsigned short* feat16 = (unsigned short*)alloc((size_t)N * HF * 2);
  unsigned short* xnb = (unsigned short*)alloc((size_t)N * 128 * 2);
  float* xinv = (float*)alloc((size_t)N * 4);
  float* h0inv = (float*)alloc((size_t)N * 4);
  float* el = (float*)alloc((size_t)N * NH * 4);
  float* er = (float*)alloc((size_t)N * NH * 4);
  float* svc = (float*)alloc((size_t)E * 4);
  int* row_start = (int*)alloc((size_t)(N + 1) * 4);
  int* row_start2 = (int*)alloc((size_t)(N + 1) * 4);
  int* csr_src = (int*)alloc((size_t)E * 4);
  int* c2src = (int*)alloc((size_t)E * 4);
  int* c2dst = (int*)alloc((size_t)E * 4);
  int* c2eid = (int*)alloc((size_t)E * 4);
  int* cs = (int*)alloc((size_t)E * 4);
  int* cd = (int*)alloc((size_t)E * 4);
  int* ce = (int*)alloc((size_t)E * 4);
  int* mask2 = (int*)alloc((size_t)E * 4);
  int* pos2 = (int*)alloc((size_t)(E + 1) * 4);
  const int NSB = (N + 1023) / 1024;  // node-scan blocks
  const int ESB = (E + 1023) / 1024;  // edge-scan blocks
  int* bsum = (int*)alloc((size_t)(NSB + 1) * 4);
  int* bsum2 = (int*)alloc((size_t)(NSB + 1) * 4);
  int* bsumE = (int*)alloc((size_t)(ESB + 1) * 4);
  // contiguous zero region: deg_i, cursor, deg2_i, cursor2, rowsum, degf
  char* zero_base = wp;
  int* deg_i = (int*)alloc((size_t)N * 4);
  int* cursor = (int*)alloc((size_t)N * 4);
  int* deg2_i = (int*)alloc((size_t)N * 4);
  int* cursor2 = (int*)alloc((size_t)N * 4);
  float* rowsum = (float*)alloc((size_t)N * 4);
  float* degf = (float*)alloc((size_t)N * 4);
  size_t zero_bytes = (size_t)(wp - zero_base);

  float* out_h = (float*)d_out;            // [N,256]
  float* out_att = out_h + (size_t)N * HF; // [E]
  float* out_self = out_att + E;           // [N]

  const int NB4 = (N + 3) / 4;        // wave-per-node grids
  const int EBT = (E + 255) / 256;    // thread-per-edge grids
  const int NBT = (N + 255) / 256;
  const int EB8 = (E + 31) / 32;      // 8-lane-group-per-edge grid

  // ---- zero accumulators (ws/d_out are poisoned before every call) ----
  hipMemsetAsync(zero_base, 0, zero_bytes, stream);
  hipMemsetAsync(out_att, 0, (size_t)E * 4, stream);

  // ---- CSR by dst (gat_agg) and by src (att_coef), fused passes ----
  hist2_kernel<<<EBT, 256, 0, stream>>>(esrc, edst, deg_i, deg2_i, E);
  {
    dim3 ga(NSB, 2);
    scanA2_kernel<<<ga, 1024, 0, stream>>>(deg_i, deg2_i, row_start,
                                           row_start2, bsum, bsum2, N);
    scanB2_kernel<<<2, 1024, 0, stream>>>(bsum, bsum2, NSB);
    dim3 gc((N + 256) / 256, 2);
    scanC2_kernel<<<gc, 256, 0, stream>>>(row_start, row_start2, bsum, bsum2,
                                          N, NSB);
  }
  scatter12_kernel<<<EBT, 256, 0, stream>>>(esrc, edst, row_start, cursor,
                                            csr_src, row_start2, cursor2,
                                            c2src, c2dst, c2eid, E);

  // ---- att_coef #1 on x: bf16 cosine mask, edge-parallel ----
  xprep_kernel<<<NB4, 256, 0, stream>>>(x, xinv, xnb, N);
  edge_mask8_kernel<<<EB8, 256, 0, stream>>>(xnb, x, xinv, c2src, c2dst,
                                             mask2, E);
  // compact survivors (deterministic prefix scan; no contended atomics)
  scanA_kernel<<<ESB, 1024, 0, stream>>>(mask2, pos2, bsumE, E);
  scanB_kernel<<<1, 1024, 0, stream>>>(bsumE, ESB);
  scanC_kernel<<<(E + 256) / 256, 256, 0, stream>>>(pos2, bsumE, E, ESB);
  compact_kernel<<<EBT, 256, 0, stream>>>(mask2, pos2, c2src, c2dst, c2eid,
                                          cs, cd, ce, E);

  // ---- layer 0: feat16/el/er = fused gemm; aggregate -> h0 ----
  {
    dim3 g((N + 127) / 128, HF / 128);
    gemm_kernel<<<g, 256, 0, stream>>>(x, W0, a0, feat16, el, er, N, 128, HF);
  }
  gat_agg_kernel<<<NB4, 256, 0, stream>>>(feat16, el, er, row_start, csr_src,
                                          b0, h0, h0inv, N, 1);

  // ---- att_coef #2 on h0 over survivors: att_w + self_w ----
  sim2_kernel<<<1024, 256, 0, stream>>>(h0, h0inv, cs, cd, pos2 + E, svc,
                                        rowsum, degf);
  att_w_kernel<<<512, 256, 0, stream>>>(svc, rowsum, cs, ce, pos2 + E,
                                        out_att);
  self_w_kernel<<<NBT, 256, 0, stream>>>(degf, out_self, N);

  // ---- layer 1: feat16/el/er = fused gemm; aggregate -> out_h ----
  {
    dim3 g((N + 127) / 128, HF / 128);
    gemm_kernel<<<g, 256, 0, stream>>>(h0, W1, a1, feat16, el, er, N, 256, HF);
  }
  gat_agg_kernel<<<NB4, 256, 0, stream>>>(feat16, el, er, row_start, csr_src,
                                          b1, out_h, nullptr, N, 0);
}

// Round 7
// 584.943 us; speedup vs baseline: 1.5525x; 1.1339x over previous
//
#include <hip/hip_runtime.h>

// GATGuard: 2-layer GAT with cosine-similarity edge gating (att_coef).
// N=50000 nodes, E=800000 raw edges, H=4 heads, F=64 feat/head, HF=256.
// Outputs: h1 [N,256], att_w [E], self_w [N]  (concatenated in d_out).
// NOTE: node ids stored as u16 in the CSR (valid since N=50000 < 65536).

#define NH 4
#define NF 64
#define HF 256

__device__ __forceinline__ float wred_sum(float v) {
#pragma unroll
  for (int o = 32; o > 0; o >>= 1) v += __shfl_xor(v, o, 64);
  return v;
}
__device__ __forceinline__ float lrelu(float x, float s) {
  return x > 0.f ? x : s * x;
}
__device__ __forceinline__ float bf2f(unsigned short u) {
  union { float f; unsigned int i; } v;
  v.i = ((unsigned int)u) << 16;
  return v.f;
}
__device__ __forceinline__ unsigned short f2bf(float f) {  // RNE
  union { float f; unsigned int i; } v;
  v.f = f;
  unsigned int r = v.i + 0x7fffu + ((v.i >> 16) & 1u);
  return (unsigned short)(r >> 16);
}
__device__ __forceinline__ float dot_bf16x8(uint4 a, uint4 b) {
  const unsigned int* pa = (const unsigned int*)&a;
  const unsigned int* pb = (const unsigned int*)&b;
  float acc = 0.f;
#pragma unroll
  for (int i = 0; i < 4; ++i) {
    acc += bf2f((unsigned short)(pa[i] & 0xffff)) *
           bf2f((unsigned short)(pb[i] & 0xffff));
    acc += bf2f((unsigned short)(pa[i] >> 16)) *
           bf2f((unsigned short)(pb[i] >> 16));
  }
  return acc;
}
__device__ __forceinline__ float4 unpack_bf4(uint2 q) {
  return make_float4(bf2f((unsigned short)(q.x & 0xffff)),
                     bf2f((unsigned short)(q.x >> 16)),
                     bf2f((unsigned short)(q.y & 0xffff)),
                     bf2f((unsigned short)(q.y >> 16)));
}

// ---- fused row-norm + normalized bf16 copy of x (wave per row, D=128) ----
__global__ __launch_bounds__(256) void xprep_kernel(
    const float* __restrict__ X, float* __restrict__ inv,
    unsigned short* __restrict__ xnb, int n) {
  int row = blockIdx.x * 4 + (threadIdx.x >> 6);
  int lane = threadIdx.x & 63;
  if (row >= n) return;
  float2 v = ((const float2*)(X + (size_t)row * 128))[lane];
  float acc = v.x * v.x + v.y * v.y;
  acc = wred_sum(acc);
  float s = 1.f / fmaxf(sqrtf(acc), 1e-12f);
  if (lane == 0) inv[row] = s;
  unsigned int packed =
      (unsigned int)f2bf(v.x * s) | ((unsigned int)f2bf(v.y * s) << 16);
  ((unsigned int*)(xnb + (size_t)row * 128))[lane] = packed;
}

// ---- layer-0 cosine mask: 8-lane group per edge, ORIGINAL edge order -----
// (no src-CSR: kills 12 B/edge of scattered writes in the CSR build; row
// gathers are L3-resident either way.)
// bf16 dot (256 B/row gathers) + exact f32 recheck near the 0.1 threshold.
__global__ __launch_bounds__(256) void edge_mask8_kernel(
    const unsigned short* __restrict__ xnb, const float* __restrict__ X,
    const float* __restrict__ xinv, const int* __restrict__ esrc,
    const int* __restrict__ edst, int* __restrict__ mask2, int E_) {
  int p = blockIdx.x * 32 + (threadIdx.x >> 3);
  int gl = threadIdx.x & 7;
  if (p >= E_) return;
  int s = esrc[p], d = edst[p];
  const uint4* ps = (const uint4*)(xnb + (size_t)s * 128);
  const uint4* pd = (const uint4*)(xnb + (size_t)d * 128);
  uint4 a0 = ps[gl], a1 = ps[gl + 8];
  uint4 b0 = pd[gl], b1 = pd[gl + 8];
  float acc = dot_bf16x8(a0, b0) + dot_bf16x8(a1, b1);
#pragma unroll
  for (int o = 1; o < 8; o <<= 1) acc += __shfl_xor(acc, o, 64);
  bool mk;
  if (fabsf(acc - 0.1f) < 4e-3f) {  // exact recheck (~2% of edges)
    const float4* fs = (const float4*)(X + (size_t)s * 128);
    const float4* fd = (const float4*)(X + (size_t)d * 128);
    float a2 = 0.f;
#pragma unroll
    for (int i = 0; i < 4; ++i) {
      float4 fa = fs[gl + 8 * i], fb = fd[gl + 8 * i];
      a2 += fa.x * fb.x + fa.y * fb.y + fa.z * fb.z + fa.w * fb.w;
    }
#pragma unroll
    for (int o = 1; o < 8; o <<= 1) a2 += __shfl_xor(a2, o, 64);
    mk = (a2 * xinv[s] * xinv[d]) >= 0.1f;
  } else {
    mk = acc >= 0.1f;
  }
  if (gl == 0) mask2[p] = mk ? 1 : 0;
}

// ---- compact surviving edges (sequential writes via prefix scan) --------
__global__ __launch_bounds__(256) void compact_kernel(
    const int* __restrict__ mask2, const int* __restrict__ pos2,
    const int* __restrict__ esrc, const int* __restrict__ edst,
    int* __restrict__ cs, int* __restrict__ cd, int* __restrict__ ce,
    int E_) {
  int p = blockIdx.x * blockDim.x + threadIdx.x;
  if (p >= E_) return;
  if (mask2[p]) {
    int q = pos2[p];
    cs[q] = esrc[p];
    cd[q] = edst[p];
    ce[q] = p;
  }
}

// ---- att_coef #2 over compacted survivors: 16-lane group per edge -------
__global__ __launch_bounds__(256) void sim2_kernel(
    const float* __restrict__ Hf, const float* __restrict__ hinv,
    const int* __restrict__ cs, const int* __restrict__ cd,
    const int* __restrict__ total, float* __restrict__ svc,
    float* __restrict__ rowsum, float* __restrict__ degf) {
  int S = total[0];
  int gl = threadIdx.x & 15;
  int g0 = blockIdx.x * 16 + (threadIdx.x >> 4);
  int gstride = gridDim.x * 16;
  for (int q = g0; q < S; q += gstride) {
    int s = cs[q], d = cd[q];
    const float4* hs = (const float4*)(Hf + (size_t)s * 256);
    const float4* hd = (const float4*)(Hf + (size_t)d * 256);
    float acc = 0.f;
#pragma unroll
    for (int i = 0; i < 4; ++i) {
      float4 a = hs[gl + 16 * i], b = hd[gl + 16 * i];
      acc += a.x * b.x + a.y * b.y + a.z * b.z + a.w * b.w;
    }
#pragma unroll
    for (int o = 1; o < 16; o <<= 1) acc += __shfl_xor(acc, o, 64);
    if (gl == 0) {
      float sim = acc * hinv[s] * hinv[d];
      float sv = (sim >= 0.1f) ? sim : 0.f;
      svc[q] = sv;
      if (sv > 0.f) {
        atomicAdd(&rowsum[s], sv);
        atomicAdd(&degf[s], 1.0f);
      }
    }
  }
}

// ---- att_w over survivors (out_att pre-zeroed) ---------------------------
__global__ __launch_bounds__(256) void att_w_kernel(
    const float* __restrict__ svc, const float* __restrict__ rowsum,
    const int* __restrict__ cs, const int* __restrict__ ce,
    const int* __restrict__ total, float* __restrict__ out_att) {
  int S = total[0];
  int stride = gridDim.x * blockDim.x;
  for (int q = blockIdx.x * blockDim.x + threadIdx.x; q < S; q += stride) {
    float sv = svc[q];
    if (sv > 0.f) out_att[ce[q]] = __expf(sv / rowsum[cs[q]]);
  }
}

// ---- self_w (thread per node) --------------------------------------------
__global__ __launch_bounds__(256) void self_w_kernel(
    const float* __restrict__ degf, float* __restrict__ out_self, int n) {
  int i = blockIdx.x * blockDim.x + threadIdx.x;
  if (i >= n) return;
  out_self[i] = __expf(1.f / (degf[i] + 1.f));
}

// ---- tiled FP32 GEMM + fused epilogue -----------------------------------
// C[n,M] = A[n,K] @ B[K,M]; 128x64 tile (grid (391,4) -> ~6 blocks/CU; the
// old 128x128 grid of 782 blocks capped occupancy at ~20%), 256 threads,
// 8x4 microtile, K-chunk 16. As padded to 132 (4-way transpose-store
// conflict -> 2-way free). Epilogue: bf16 feat16 store + exact f32 el/er
// (block covers exactly one head = blockIdx.y).
__global__ __launch_bounds__(256) void gemm_kernel(
    const float* __restrict__ A, const float* __restrict__ B,
    const float* __restrict__ Av, unsigned short* __restrict__ feat16,
    float* __restrict__ el, float* __restrict__ er, int n, int K, int M) {
  __shared__ float As[16][132];
  __shared__ float Bs[16][64];
  int tid = threadIdx.x;
  int tx = tid & 15, ty = tid >> 4;
  int row0 = blockIdx.x * 128;
  int col0 = blockIdx.y * 64;
  int h = blockIdx.y;  // head (M=256, 64 cols per head)
  float acc[8][4] = {};
  for (int k0 = 0; k0 < K; k0 += 16) {
    // A tile: 128 rows x 16 k = 512 float4, transpose into As[k][row]
#pragma unroll
    for (int i = 0; i < 2; ++i) {
      int p = tid + i * 256;
      int r = p >> 2, c4 = p & 3;
      int gr = row0 + r;
      float4 v = make_float4(0.f, 0.f, 0.f, 0.f);
      if (gr < n) v = *(const float4*)(A + (size_t)gr * K + k0 + c4 * 4);
      As[c4 * 4 + 0][r] = v.x;
      As[c4 * 4 + 1][r] = v.y;
      As[c4 * 4 + 2][r] = v.z;
      As[c4 * 4 + 3][r] = v.w;
    }
    // B tile: 16 rows x 64 cols = 256 float4, sequential (conflict-free)
    {
      int r = tid >> 4, c4 = tid & 15;
      *(float4*)&Bs[r][c4 * 4] =
          *(const float4*)(B + (size_t)(k0 + r) * M + col0 + c4 * 4);
    }
    __syncthreads();
#pragma unroll
    for (int k = 0; k < 16; ++k) {
      float4 a0v = *(const float4*)&As[k][ty * 4];
      float4 a1v = *(const float4*)&As[k][64 + ty * 4];
      float4 bv4 = *(const float4*)&Bs[k][tx * 4];
      float av[8] = {a0v.x, a0v.y, a0v.z, a0v.w, a1v.x, a1v.y, a1v.z, a1v.w};
      float bv[4] = {bv4.x, bv4.y, bv4.z, bv4.w};
#pragma unroll
      for (int i = 0; i < 8; ++i)
#pragma unroll
        for (int j = 0; j < 4; ++j) acc[i][j] += av[i] * bv[j];
    }
    __syncthreads();
  }
  // attention-vector coefficients for this thread's 4 columns (head h)
  float aEl[4], aEr[4];
#pragma unroll
  for (int j = 0; j < 4; ++j) {
    aEl[j] = Av[h * 64 + tx * 4 + j];
    aEr[j] = Av[HF + h * 64 + tx * 4 + j];
  }
#pragma unroll
  for (int half = 0; half < 2; ++half) {
#pragma unroll
    for (int i = 0; i < 4; ++i) {
      int gr = row0 + half * 64 + ty * 4 + i;
      int ai = half * 4 + i;
      float pl = 0.f, pr = 0.f;
#pragma unroll
      for (int j = 0; j < 4; ++j) {
        pl += acc[ai][j] * aEl[j];
        pr += acc[ai][j] * aEr[j];
      }
#pragma unroll
      for (int o = 1; o < 16; o <<= 1) {
        pl += __shfl_xor(pl, o, 64);
        pr += __shfl_xor(pr, o, 64);
      }
      if (gr < n) {
        unsigned int p0 = (unsigned int)f2bf(acc[ai][0]) |
                          ((unsigned int)f2bf(acc[ai][1]) << 16);
        unsigned int p1 = (unsigned int)f2bf(acc[ai][2]) |
                          ((unsigned int)f2bf(acc[ai][3]) << 16);
        ((uint2*)(feat16 + (size_t)gr * HF + col0 + tx * 4))[0] =
            make_uint2(p0, p1);
        if (tx == 0) {
          el[gr * NH + h] = pl;
          er[gr * NH + h] = pr;
        }
      }
    }
  }
}

// ---------------- CSR build (dst only; 2 B/edge scattered) ----------------
__global__ __launch_bounds__(256) void hist_kernel(
    const int* __restrict__ key, int* __restrict__ deg, int E_) {
  int e = blockIdx.x * blockDim.x + threadIdx.x;
  if (e >= E_) return;
  atomicAdd(&deg[key[e]], 1);
}

// 3-phase scan: per-block scan -> parallel scan of block sums -> add offsets.
__global__ __launch_bounds__(1024) void scanA_kernel(
    const int* __restrict__ deg, int* __restrict__ rs, int* __restrict__ bsum,
    int n) {
  __shared__ int temp[1024];
  int tid = threadIdx.x;
  int idx = blockIdx.x * 1024 + tid;
  int v = (idx < n) ? deg[idx] : 0;
  temp[tid] = v;
  __syncthreads();
  for (int off = 1; off < 1024; off <<= 1) {
    int t = (tid >= off) ? temp[tid - off] : 0;
    __syncthreads();
    temp[tid] += t;
    __syncthreads();
  }
  if (idx < n) rs[idx] = temp[tid] - v;  // block-local exclusive
  if (tid == 1023) bsum[blockIdx.x] = temp[1023];
}

__global__ __launch_bounds__(1024) void scanB_kernel(int* __restrict__ bsum,
                                                     int nb) {
  __shared__ int t[1024];
  int tid = threadIdx.x;
  int v = (tid < nb) ? bsum[tid] : 0;
  t[tid] = v;
  __syncthreads();
  for (int off = 1; off < 1024; off <<= 1) {
    int u = (tid >= off) ? t[tid - off] : 0;
    __syncthreads();
    t[tid] += u;
    __syncthreads();
  }
  if (tid < nb) bsum[tid] = t[tid] - v;  // exclusive
  if (tid == 0) bsum[nb] = t[1023];      // total
}

__global__ __launch_bounds__(256) void scanC_kernel(
    int* __restrict__ rs, const int* __restrict__ bsum, int n, int nb) {
  int idx = blockIdx.x * blockDim.x + threadIdx.x;
  if (idx < n) rs[idx] += bsum[idx >> 10];
  else if (idx == n) rs[n] = bsum[nb];
}

__global__ __launch_bounds__(256) void scatter_kernel(
    const int* __restrict__ src, const int* __restrict__ dst,
    const int* __restrict__ rs, int* __restrict__ cursor,
    unsigned short* __restrict__ csr_src, int E_) {
  int e = blockIdx.x * blockDim.x + threadIdx.x;
  if (e >= E_) return;
  int d = dst[e];
  int pos = rs[d] + atomicAdd(&cursor[d], 1);
  csr_src[pos] = (unsigned short)src[e];
}

// ---------------- GAT aggregation (wave per node, bf16 gathers) ----------
// lane l: features 4l..4l+3 (uint2 = 4 bf16, 8 B/lane -> 512 B/row).
// 8 CSR indices (u16) prefetched per lane-group and shfl-broadcast so the
// 8 row gathers issue back-to-back. No segment-max (scores O(1); exp safe).
__global__ __launch_bounds__(256) void gat_agg_kernel(
    const unsigned short* __restrict__ feat16, const float* __restrict__ el,
    const float* __restrict__ er, const int* __restrict__ row_start,
    const unsigned short* __restrict__ csr_src,
    const float* __restrict__ bias, float* __restrict__ out,
    float* __restrict__ inv_out, int n, int act) {
  int node = blockIdx.x * 4 + (threadIdx.x >> 6);
  int lane = threadIdx.x & 63;
  if (node >= n) return;
  int h = lane >> 4;
  const uint2* f16 = (const uint2*)feat16;
  float er_n = er[node * NH + h];
  float es = lrelu(el[node * NH + h] + er_n, 0.2f);
  int start = row_start[node];
  int deg = row_start[node + 1] - start;
  float ws = __expf(es);
  float4 fv = unpack_bf4(f16[(size_t)node * 64 + lane]);
  float4 facc = make_float4(ws * fv.x, ws * fv.y, ws * fv.z, ws * fv.w);
  float z = ws;
  for (int c = 0; c < deg; c += 8) {
    int t = c + (lane & 7);
    int myidx = (t < deg) ? (int)csr_src[start + t] : 0;
    if (deg - c >= 8) {
#pragma unroll
      for (int j = 0; j < 8; ++j) {
        int s = __shfl(myidx, j, 8);
        float w = __expf(lrelu(el[s * NH + h] + er_n, 0.2f));
        float4 f = unpack_bf4(f16[(size_t)s * 64 + lane]);
        facc.x += w * f.x;
        facc.y += w * f.y;
        facc.z += w * f.z;
        facc.w += w * f.w;
        z += w;
      }
    } else {
      int m8 = deg - c;
      for (int j = 0; j < m8; ++j) {
        int s = __shfl(myidx, j, 8);
        float w = __expf(lrelu(el[s * NH + h] + er_n, 0.2f));
        float4 f = unpack_bf4(f16[(size_t)s * 64 + lane]);
        facc.x += w * f.x;
        facc.y += w * f.y;
        facc.z += w * f.z;
        facc.w += w * f.w;
        z += w;
      }
    }
  }
  float rz = 1.f / z;
  float4 bb = ((const float4*)bias)[lane];
  float4 o_;
  o_.x = facc.x * rz + bb.x;
  o_.y = facc.y * rz + bb.y;
  o_.z = facc.z * rz + bb.z;
  o_.w = facc.w * rz + bb.w;
  if (act) {
    o_.x = lrelu(o_.x, 0.01f);
    o_.y = lrelu(o_.y, 0.01f);
    o_.z = lrelu(o_.z, 0.01f);
    o_.w = lrelu(o_.w, 0.01f);
  }
  ((float4*)out)[(size_t)node * 64 + lane] = o_;
  if (inv_out) {  // fused row-norm for the next att_coef
    float sq = o_.x * o_.x + o_.y * o_.y + o_.z * o_.z + o_.w * o_.w;
    sq = wred_sum(sq);
    if (lane == 0) inv_out[node] = 1.f / fmaxf(sqrtf(sq), 1e-12f);
  }
}

extern "C" void kernel_launch(void* const* d_in, const int* in_sizes, int n_in,
                              void* d_out, int out_size, void* d_ws, size_t ws_size,
                              hipStream_t stream) {
  const float* x = (const float*)d_in[0];
  const int* esrc = (const int*)d_in[1];
  const int* edst = (const int*)d_in[2];
  const float* W0 = (const float*)d_in[3];
  const float* a0 = (const float*)d_in[4];
  const float* b0 = (const float*)d_in[5];
  const float* W1 = (const float*)d_in[6];
  const float* a1 = (const float*)d_in[7];
  const float* b1 = (const float*)d_in[8];

  const int N = in_sizes[0] / 128;  // 50000
  const int E = in_sizes[1];        // 800000

  // ---- workspace layout (256B aligned chunks) ----
  char* wp = (char*)d_ws;
  auto alloc = [&](size_t bytes) {
    char* p = wp;
    wp += (bytes + 255) & ~(size_t)255;
    return p;
  };
  float* h0 = (float*)alloc((size_t)N * HF * 4);
  unsigned short* feat16 = (unsigned short*)alloc((size_t)N * HF * 2);
  unsigned short* xnb = (unsigned short*)alloc((size_t)N * 128 * 2);
  float* xinv = (float*)alloc((size_t)N * 4);
  float* h0inv = (float*)alloc((size_t)N * 4);
  float* el = (float*)alloc((size_t)N * NH * 4);
  float* er = (float*)alloc((size_t)N * NH * 4);
  float* svc = (float*)alloc((size_t)E * 4);
  int* row_start = (int*)alloc((size_t)(N + 1) * 4);
  unsigned short* csr_src = (unsigned short*)alloc((size_t)E * 2);
  int* cs = (int*)alloc((size_t)E * 4);
  int* cd = (int*)alloc((size_t)E * 4);
  int* ce = (int*)alloc((size_t)E * 4);
  int* mask2 = (int*)alloc((size_t)E * 4);
  int* pos2 = (int*)alloc((size_t)(E + 1) * 4);
  const int NSB = (N + 1023) / 1024;  // node-scan blocks
  const int ESB = (E + 1023) / 1024;  // edge-scan blocks
  int* bsum = (int*)alloc((size_t)(NSB + 1) * 4);
  int* bsumE = (int*)alloc((size_t)(ESB + 1) * 4);
  // contiguous zero region: deg_i, cursor, rowsum, degf
  char* zero_base = wp;
  int* deg_i = (int*)alloc((size_t)N * 4);
  int* cursor = (int*)alloc((size_t)N * 4);
  float* rowsum = (float*)alloc((size_t)N * 4);
  float* degf = (float*)alloc((size_t)N * 4);
  size_t zero_bytes = (size_t)(wp - zero_base);

  float* out_h = (float*)d_out;            // [N,256]
  float* out_att = out_h + (size_t)N * HF; // [E]
  float* out_self = out_att + E;           // [N]

  const int NB4 = (N + 3) / 4;        // wave-per-node grids
  const int EBT = (E + 255) / 256;    // thread-per-edge grids
  const int NBT = (N + 255) / 256;
  const int EB8 = (E + 31) / 32;      // 8-lane-group-per-edge grid

  // ---- zero accumulators (ws/d_out are poisoned before every call) ----
  hipMemsetAsync(zero_base, 0, zero_bytes, stream);
  hipMemsetAsync(out_att, 0, (size_t)E * 4, stream);

  // ---- CSR by dst (u16 payload; src-CSR eliminated) ----
  hist_kernel<<<EBT, 256, 0, stream>>>(edst, deg_i, E);
  scanA_kernel<<<NSB, 1024, 0, stream>>>(deg_i, row_start, bsum, N);
  scanB_kernel<<<1, 1024, 0, stream>>>(bsum, NSB);
  scanC_kernel<<<(N + 256) / 256, 256, 0, stream>>>(row_start, bsum, N, NSB);
  scatter_kernel<<<EBT, 256, 0, stream>>>(esrc, edst, row_start, cursor,
                                          csr_src, E);

  // ---- att_coef #1 on x: bf16 cosine mask (edge order) + compaction ----
  xprep_kernel<<<NB4, 256, 0, stream>>>(x, xinv, xnb, N);
  edge_mask8_kernel<<<EB8, 256, 0, stream>>>(xnb, x, xinv, esrc, edst, mask2,
                                             E);
  scanA_kernel<<<ESB, 1024, 0, stream>>>(mask2, pos2, bsumE, E);
  scanB_kernel<<<1, 1024, 0, stream>>>(bsumE, ESB);
  scanC_kernel<<<(E + 256) / 256, 256, 0, stream>>>(pos2, bsumE, E, ESB);
  compact_kernel<<<EBT, 256, 0, stream>>>(mask2, pos2, esrc, edst, cs, cd, ce,
                                          E);

  // ---- layer 0: feat16/el/er = fused gemm; aggregate -> h0 ----
  {
    dim3 g((N + 127) / 128, HF / 64);
    gemm_kernel<<<g, 256, 0, stream>>>(x, W0, a0, feat16, el, er, N, 128, HF);
  }
  gat_agg_kernel<<<NB4, 256, 0, stream>>>(feat16, el, er, row_start, csr_src,
                                          b0, h0, h0inv, N, 1);

  // ---- att_coef #2 on h0 over survivors: att_w + self_w ----
  sim2_kernel<<<1024, 256, 0, stream>>>(h0, h0inv, cs, cd, pos2 + E, svc,
                                        rowsum, degf);
  att_w_kernel<<<512, 256, 0, stream>>>(svc, rowsum, cs, ce, pos2 + E,
                                        out_att);
  self_w_kernel<<<NBT, 256, 0, stream>>>(degf, out_self, N);

  // ---- layer 1: feat16/el/er = fused gemm; aggregate -> out_h ----
  {
    dim3 g((N + 127) / 128, HF / 64);
    gemm_kernel<<<g, 256, 0, stream>>>(h0, W1, a1, feat16, el, er, N, 256, HF);
  }
  gat_agg_kernel<<<NB4, 256, 0, stream>>>(feat16, el, er, row_start, csr_src,
                                          b1, out_h, nullptr, N, 0);
}

// Round 8
// 491.228 us; speedup vs baseline: 1.8487x; 1.1908x over previous
//
#include <hip/hip_runtime.h>

// GATGuard: 2-layer GAT with cosine-similarity edge gating (att_coef).
// N=50000 nodes, E=800000 raw edges, H=4 heads, F=64 feat/head, HF=256.
// Outputs: h1 [N,256], att_w [E], self_w [N]  (concatenated in d_out).
// GEMMs run on the matrix pipe: f16-input MFMA (error ~6e-4, below the
// bf16 feat16 storage rounding already in the pipeline).

#define NH 4
#define NF 64
#define HF 256

typedef _Float16 f16x8 __attribute__((ext_vector_type(8)));
typedef _Float16 f16x4 __attribute__((ext_vector_type(4)));
typedef float f32x4 __attribute__((ext_vector_type(4)));

__device__ __forceinline__ float wred_sum(float v) {
#pragma unroll
  for (int o = 32; o > 0; o >>= 1) v += __shfl_xor(v, o, 64);
  return v;
}
__device__ __forceinline__ float lrelu(float x, float s) {
  return x > 0.f ? x : s * x;
}
__device__ __forceinline__ float bf2f(unsigned short u) {
  union { float f; unsigned int i; } v;
  v.i = ((unsigned int)u) << 16;
  return v.f;
}
__device__ __forceinline__ unsigned short f2bf(float f) {  // RNE
  union { float f; unsigned int i; } v;
  v.f = f;
  unsigned int r = v.i + 0x7fffu + ((v.i >> 16) & 1u);
  return (unsigned short)(r >> 16);
}
__device__ __forceinline__ float dot_bf16x8(uint4 a, uint4 b) {
  const unsigned int* pa = (const unsigned int*)&a;
  const unsigned int* pb = (const unsigned int*)&b;
  float acc = 0.f;
#pragma unroll
  for (int i = 0; i < 4; ++i) {
    acc += bf2f((unsigned short)(pa[i] & 0xffff)) *
           bf2f((unsigned short)(pb[i] & 0xffff));
    acc += bf2f((unsigned short)(pa[i] >> 16)) *
           bf2f((unsigned short)(pb[i] >> 16));
  }
  return acc;
}
__device__ __forceinline__ float4 unpack_bf4(uint2 q) {
  return make_float4(bf2f((unsigned short)(q.x & 0xffff)),
                     bf2f((unsigned short)(q.x >> 16)),
                     bf2f((unsigned short)(q.y & 0xffff)),
                     bf2f((unsigned short)(q.y >> 16)));
}

// ---- fused row-norm + normalized bf16 copy + raw f16 copy of x ----------
__global__ __launch_bounds__(256) void xprep_kernel(
    const float* __restrict__ X, float* __restrict__ inv,
    unsigned short* __restrict__ xnb, _Float16* __restrict__ x16, int n) {
  int row = blockIdx.x * 4 + (threadIdx.x >> 6);
  int lane = threadIdx.x & 63;
  if (row >= n) return;
  float2 v = ((const float2*)(X + (size_t)row * 128))[lane];
  float acc = v.x * v.x + v.y * v.y;
  acc = wred_sum(acc);
  float s = 1.f / fmaxf(sqrtf(acc), 1e-12f);
  if (lane == 0) inv[row] = s;
  unsigned int packed =
      (unsigned int)f2bf(v.x * s) | ((unsigned int)f2bf(v.y * s) << 16);
  ((unsigned int*)(xnb + (size_t)row * 128))[lane] = packed;
  _Float16 h0v = (_Float16)v.x, h1v = (_Float16)v.y;
  x16[(size_t)row * 128 + 2 * lane] = h0v;
  x16[(size_t)row * 128 + 2 * lane + 1] = h1v;
}

// ---- layer-0 cosine mask: 8-lane group per edge, original edge order ----
__global__ __launch_bounds__(256) void edge_mask8_kernel(
    const unsigned short* __restrict__ xnb, const float* __restrict__ X,
    const float* __restrict__ xinv, const int* __restrict__ esrc,
    const int* __restrict__ edst, int* __restrict__ mask2, int E_) {
  int p = blockIdx.x * 32 + (threadIdx.x >> 3);
  int gl = threadIdx.x & 7;
  if (p >= E_) return;
  int s = esrc[p], d = edst[p];
  const uint4* ps = (const uint4*)(xnb + (size_t)s * 128);
  const uint4* pd = (const uint4*)(xnb + (size_t)d * 128);
  uint4 a0 = ps[gl], a1 = ps[gl + 8];
  uint4 b0 = pd[gl], b1 = pd[gl + 8];
  float acc = dot_bf16x8(a0, b0) + dot_bf16x8(a1, b1);
#pragma unroll
  for (int o = 1; o < 8; o <<= 1) acc += __shfl_xor(acc, o, 64);
  bool mk;
  if (fabsf(acc - 0.1f) < 4e-3f) {  // exact recheck (~2% of edges)
    const float4* fs = (const float4*)(X + (size_t)s * 128);
    const float4* fd = (const float4*)(X + (size_t)d * 128);
    float a2 = 0.f;
#pragma unroll
    for (int i = 0; i < 4; ++i) {
      float4 fa = fs[gl + 8 * i], fb = fd[gl + 8 * i];
      a2 += fa.x * fb.x + fa.y * fb.y + fa.z * fb.z + fa.w * fb.w;
    }
#pragma unroll
    for (int o = 1; o < 8; o <<= 1) a2 += __shfl_xor(a2, o, 64);
    mk = (a2 * xinv[s] * xinv[d]) >= 0.1f;
  } else {
    mk = acc >= 0.1f;
  }
  if (gl == 0) mask2[p] = mk ? 1 : 0;
}

// ---- compact surviving edges (sequential writes via prefix scan) --------
__global__ __launch_bounds__(256) void compact_kernel(
    const int* __restrict__ mask2, const int* __restrict__ pos2,
    const int* __restrict__ esrc, const int* __restrict__ edst,
    int* __restrict__ cs, int* __restrict__ cd, int* __restrict__ ce,
    int E_) {
  int p = blockIdx.x * blockDim.x + threadIdx.x;
  if (p >= E_) return;
  if (mask2[p]) {
    int q = pos2[p];
    cs[q] = esrc[p];
    cd[q] = edst[p];
    ce[q] = p;
  }
}

// ---- att_coef #2 over compacted survivors: 16-lane group per edge -------
__global__ __launch_bounds__(256) void sim2_kernel(
    const float* __restrict__ Hf, const float* __restrict__ hinv,
    const int* __restrict__ cs, const int* __restrict__ cd,
    const int* __restrict__ total, float* __restrict__ svc,
    float* __restrict__ rowsum, float* __restrict__ degf) {
  int S = total[0];
  int gl = threadIdx.x & 15;
  int g0 = blockIdx.x * 16 + (threadIdx.x >> 4);
  int gstride = gridDim.x * 16;
  for (int q = g0; q < S; q += gstride) {
    int s = cs[q], d = cd[q];
    const float4* hs = (const float4*)(Hf + (size_t)s * 256);
    const float4* hd = (const float4*)(Hf + (size_t)d * 256);
    float acc = 0.f;
#pragma unroll
    for (int i = 0; i < 4; ++i) {
      float4 a = hs[gl + 16 * i], b = hd[gl + 16 * i];
      acc += a.x * b.x + a.y * b.y + a.z * b.z + a.w * b.w;
    }
#pragma unroll
    for (int o = 1; o < 16; o <<= 1) acc += __shfl_xor(acc, o, 64);
    if (gl == 0) {
      float sim = acc * hinv[s] * hinv[d];
      float sv = (sim >= 0.1f) ? sim : 0.f;
      svc[q] = sv;
      if (sv > 0.f) {
        atomicAdd(&rowsum[s], sv);
        atomicAdd(&degf[s], 1.0f);
      }
    }
  }
}

// ---- att_w over survivors (out_att pre-zeroed) ---------------------------
__global__ __launch_bounds__(256) void att_w_kernel(
    const float* __restrict__ svc, const float* __restrict__ rowsum,
    const int* __restrict__ cs, const int* __restrict__ ce,
    const int* __restrict__ total, float* __restrict__ out_att) {
  int S = total[0];
  int stride = gridDim.x * blockDim.x;
  for (int q = blockIdx.x * blockDim.x + threadIdx.x; q < S; q += stride) {
    float sv = svc[q];
    if (sv > 0.f) out_att[ce[q]] = __expf(sv / rowsum[cs[q]]);
  }
}

// ---- self_w (thread per node) --------------------------------------------
__global__ __launch_bounds__(256) void self_w_kernel(
    const float* __restrict__ degf, float* __restrict__ out_self, int n) {
  int i = blockIdx.x * blockDim.x + threadIdx.x;
  if (i >= n) return;
  out_self[i] = __expf(1.f / (degf[i] + 1.f));
}

// ---- pack W (f32 [K,256]) into MFMA-fragment-ordered f16 -----------------
// Wf unit u = ((h*4+tc)*KC + kc)*64 + lane holds the 8 f16 the lane feeds
// to mfma_f32_16x16x32_f16 as the B operand: B[kc*32+8*(l>>4)+j][col],
// col = h*64 + tc*16 + (l&15).
__global__ __launch_bounds__(256) void wpack_kernel(
    const float* __restrict__ W, _Float16* __restrict__ Wf, int K) {
  int KC = K >> 5;
  int u = blockIdx.x * 256 + threadIdx.x;
  int total = 16 * KC * 64;
  if (u >= total) return;
  int l = u & 63;
  int kc = (u >> 6) % KC;
  int htc = (u >> 6) / KC;  // h*4 + tc
  int col = (htc >> 2) * 64 + (htc & 3) * 16 + (l & 15);
  int kb = kc * 32 + (l >> 4) * 8;
  f16x8 o;
#pragma unroll
  for (int j = 0; j < 8; ++j) o[j] = (_Float16)W[(size_t)(kb + j) * HF + col];
  *(f16x8*)(Wf + (size_t)u * 8) = o;
}

// ---- MFMA GEMM + fused epilogue (NO LDS, no barriers) --------------------
// C[n,256] = A16[n,K] @ W; block = 128 rows x 1 head (blockIdx.y), 4 waves,
// wave = 32 rows x 64 cols = 8 tiles of 16x16, K-step 32.
// A-frags: direct global 16B/lane (L2-resident); B-frags: one coalesced
// 16B/lane load from the fragment-packed Wf (L1-hot).
// Epilogue: bf16 feat16 + exact f32 el/er from the f32 accumulators.
// C/D layout: col = lane&15, row = (lane>>4)*4 + reg (verified mapping).
__global__ __launch_bounds__(256) void gemm_mfma_kernel(
    const _Float16* __restrict__ A16, const _Float16* __restrict__ Wf,
    const float* __restrict__ Av, unsigned short* __restrict__ feat16,
    float* __restrict__ el, float* __restrict__ er, int n, int K) {
  int wave = threadIdx.x >> 6;
  int lane = threadIdx.x & 63;
  int h = blockIdx.y;
  int row0 = blockIdx.x * 128 + wave * 32;
  int KC = K >> 5;
  int rA = lane & 15, gk = lane >> 4;
  f32x4 acc[2][4] = {};
  const _Float16* a0p =
      A16 + (size_t)min(row0 + rA, n - 1) * K + gk * 8;
  const _Float16* a1p =
      A16 + (size_t)min(row0 + 16 + rA, n - 1) * K + gk * 8;
  const f16x8* bf = (const f16x8*)(Wf + (size_t)h * 4 * KC * 512);
  for (int kc = 0; kc < KC; ++kc) {
    f16x8 af0 = *(const f16x8*)(a0p + kc * 32);
    f16x8 af1 = *(const f16x8*)(a1p + kc * 32);
#pragma unroll
    for (int tc = 0; tc < 4; ++tc) {
      f16x8 bfr = bf[(tc * KC + kc) * 64 + lane];
      acc[0][tc] =
          __builtin_amdgcn_mfma_f32_16x16x32_f16(af0, bfr, acc[0][tc], 0, 0, 0);
      acc[1][tc] =
          __builtin_amdgcn_mfma_f32_16x16x32_f16(af1, bfr, acc[1][tc], 0, 0, 0);
    }
  }
  float aEl[4], aEr[4];
#pragma unroll
  for (int tc = 0; tc < 4; ++tc) {
    aEl[tc] = Av[h * 64 + tc * 16 + rA];
    aEr[tc] = Av[HF + h * 64 + tc * 16 + rA];
  }
#pragma unroll
  for (int tr = 0; tr < 2; ++tr) {
#pragma unroll
    for (int r = 0; r < 4; ++r) {
      int row = row0 + tr * 16 + gk * 4 + r;
      float pl = 0.f, pr = 0.f;
#pragma unroll
      for (int tc = 0; tc < 4; ++tc) {
        float v = acc[tr][tc][r];
        pl += v * aEl[tc];
        pr += v * aEr[tc];
      }
#pragma unroll
      for (int o = 1; o < 16; o <<= 1) {
        pl += __shfl_xor(pl, o, 64);
        pr += __shfl_xor(pr, o, 64);
      }
      if (row < n) {
#pragma unroll
        for (int tc = 0; tc < 4; ++tc)
          feat16[(size_t)row * HF + h * 64 + tc * 16 + rA] =
              f2bf(acc[tr][tc][r]);
        if (rA == 0) {
          el[row * NH + h] = pl;
          er[row * NH + h] = pr;
        }
      }
    }
  }
}

// ---------------- CSR build (dst only; 2 B/edge scattered) ----------------
__global__ __launch_bounds__(256) void hist_kernel(
    const int* __restrict__ key, int* __restrict__ deg, int E_) {
  int e = blockIdx.x * blockDim.x + threadIdx.x;
  if (e >= E_) return;
  atomicAdd(&deg[key[e]], 1);
}

__global__ __launch_bounds__(1024) void scanA_kernel(
    const int* __restrict__ deg, int* __restrict__ rs, int* __restrict__ bsum,
    int n) {
  __shared__ int temp[1024];
  int tid = threadIdx.x;
  int idx = blockIdx.x * 1024 + tid;
  int v = (idx < n) ? deg[idx] : 0;
  temp[tid] = v;
  __syncthreads();
  for (int off = 1; off < 1024; off <<= 1) {
    int t = (tid >= off) ? temp[tid - off] : 0;
    __syncthreads();
    temp[tid] += t;
    __syncthreads();
  }
  if (idx < n) rs[idx] = temp[tid] - v;  // block-local exclusive
  if (tid == 1023) bsum[blockIdx.x] = temp[1023];
}

__global__ __launch_bounds__(1024) void scanB_kernel(int* __restrict__ bsum,
                                                     int nb) {
  __shared__ int t[1024];
  int tid = threadIdx.x;
  int v = (tid < nb) ? bsum[tid] : 0;
  t[tid] = v;
  __syncthreads();
  for (int off = 1; off < 1024; off <<= 1) {
    int u = (tid >= off) ? t[tid - off] : 0;
    __syncthreads();
    t[tid] += u;
    __syncthreads();
  }
  if (tid < nb) bsum[tid] = t[tid] - v;  // exclusive
  if (tid == 0) bsum[nb] = t[1023];      // total
}

__global__ __launch_bounds__(256) void scanC_kernel(
    int* __restrict__ rs, const int* __restrict__ bsum, int n, int nb) {
  int idx = blockIdx.x * blockDim.x + threadIdx.x;
  if (idx < n) rs[idx] += bsum[idx >> 10];
  else if (idx == n) rs[n] = bsum[nb];
}

__global__ __launch_bounds__(256) void scatter_kernel(
    const int* __restrict__ src, const int* __restrict__ dst,
    const int* __restrict__ rs, int* __restrict__ cursor,
    unsigned short* __restrict__ csr_src, int E_) {
  int e = blockIdx.x * blockDim.x + threadIdx.x;
  if (e >= E_) return;
  int d = dst[e];
  int pos = rs[d] + atomicAdd(&cursor[d], 1);
  csr_src[pos] = (unsigned short)src[e];
}

// ---------------- GAT aggregation (wave per node, bf16 gathers) ----------
__global__ __launch_bounds__(256) void gat_agg_kernel(
    const unsigned short* __restrict__ feat16, const float* __restrict__ el,
    const float* __restrict__ er, const int* __restrict__ row_start,
    const unsigned short* __restrict__ csr_src,
    const float* __restrict__ bias, float* __restrict__ out,
    float* __restrict__ inv_out, _Float16* __restrict__ h016, int n,
    int act) {
  int node = blockIdx.x * 4 + (threadIdx.x >> 6);
  int lane = threadIdx.x & 63;
  if (node >= n) return;
  int h = lane >> 4;
  const uint2* f16 = (const uint2*)feat16;
  float er_n = er[node * NH + h];
  float es = lrelu(el[node * NH + h] + er_n, 0.2f);
  int start = row_start[node];
  int deg = row_start[node + 1] - start;
  float ws = __expf(es);
  float4 fv = unpack_bf4(f16[(size_t)node * 64 + lane]);
  float4 facc = make_float4(ws * fv.x, ws * fv.y, ws * fv.z, ws * fv.w);
  float z = ws;
  for (int c = 0; c < deg; c += 8) {
    int t = c + (lane & 7);
    int myidx = (t < deg) ? (int)csr_src[start + t] : 0;
    if (deg - c >= 8) {
#pragma unroll
      for (int j = 0; j < 8; ++j) {
        int s = __shfl(myidx, j, 8);
        float w = __expf(lrelu(el[s * NH + h] + er_n, 0.2f));
        float4 f = unpack_bf4(f16[(size_t)s * 64 + lane]);
        facc.x += w * f.x;
        facc.y += w * f.y;
        facc.z += w * f.z;
        facc.w += w * f.w;
        z += w;
      }
    } else {
      int m8 = deg - c;
      for (int j = 0; j < m8; ++j) {
        int s = __shfl(myidx, j, 8);
        float w = __expf(lrelu(el[s * NH + h] + er_n, 0.2f));
        float4 f = unpack_bf4(f16[(size_t)s * 64 + lane]);
        facc.x += w * f.x;
        facc.y += w * f.y;
        facc.z += w * f.z;
        facc.w += w * f.w;
        z += w;
      }
    }
  }
  float rz = 1.f / z;
  float4 bb = ((const float4*)bias)[lane];
  float4 o_;
  o_.x = facc.x * rz + bb.x;
  o_.y = facc.y * rz + bb.y;
  o_.z = facc.z * rz + bb.z;
  o_.w = facc.w * rz + bb.w;
  if (act) {
    o_.x = lrelu(o_.x, 0.01f);
    o_.y = lrelu(o_.y, 0.01f);
    o_.z = lrelu(o_.z, 0.01f);
    o_.w = lrelu(o_.w, 0.01f);
  }
  ((float4*)out)[(size_t)node * 64 + lane] = o_;
  if (inv_out) {  // layer 0: fused row-norm + f16 copy for the next GEMM
    f16x4 hv;
    hv[0] = (_Float16)o_.x;
    hv[1] = (_Float16)o_.y;
    hv[2] = (_Float16)o_.z;
    hv[3] = (_Float16)o_.w;
    *(f16x4*)(h016 + (size_t)node * HF + lane * 4) = hv;
    float sq = o_.x * o_.x + o_.y * o_.y + o_.z * o_.z + o_.w * o_.w;
    sq = wred_sum(sq);
    if (lane == 0) inv_out[node] = 1.f / fmaxf(sqrtf(sq), 1e-12f);
  }
}

extern "C" void kernel_launch(void* const* d_in, const int* in_sizes, int n_in,
                              void* d_out, int out_size, void* d_ws, size_t ws_size,
                              hipStream_t stream) {
  const float* x = (const float*)d_in[0];
  const int* esrc = (const int*)d_in[1];
  const int* edst = (const int*)d_in[2];
  const float* W0 = (const float*)d_in[3];
  const float* a0 = (const float*)d_in[4];
  const float* b0 = (const float*)d_in[5];
  const float* W1 = (const float*)d_in[6];
  const float* a1 = (const float*)d_in[7];
  const float* b1 = (const float*)d_in[8];

  const int N = in_sizes[0] / 128;  // 50000
  const int E = in_sizes[1];        // 800000

  // ---- workspace layout (256B aligned chunks) ----
  char* wp = (char*)d_ws;
  auto alloc = [&](size_t bytes) {
    char* p = wp;
    wp += (bytes + 255) & ~(size_t)255;
    return p;
  };
  float* h0 = (float*)alloc((size_t)N * HF * 4);
  unsigned short* feat16 = (unsigned short*)alloc((size_t)N * HF * 2);
  unsigned short* xnb = (unsigned short*)alloc((size_t)N * 128 * 2);
  _Float16* x16 = (_Float16*)alloc((size_t)N * 128 * 2);
  _Float16* h016 = (_Float16*)alloc((size_t)N * HF * 2);
  _Float16* Wf0 = (_Float16*)alloc((size_t)128 * HF * 2);
  _Float16* Wf1 = (_Float16*)alloc((size_t)256 * HF * 2);
  float* xinv = (float*)alloc((size_t)N * 4);
  float* h0inv = (float*)alloc((size_t)N * 4);
  float* el = (float*)alloc((size_t)N * NH * 4);
  float* er = (float*)alloc((size_t)N * NH * 4);
  float* svc = (float*)alloc((size_t)E * 4);
  int* row_start = (int*)alloc((size_t)(N + 1) * 4);
  unsigned short* csr_src = (unsigned short*)alloc((size_t)E * 2);
  int* cs = (int*)alloc((size_t)E * 4);
  int* cd = (int*)alloc((size_t)E * 4);
  int* ce = (int*)alloc((size_t)E * 4);
  int* mask2 = (int*)alloc((size_t)E * 4);
  int* pos2 = (int*)alloc((size_t)(E + 1) * 4);
  const int NSB = (N + 1023) / 1024;  // node-scan blocks
  const int ESB = (E + 1023) / 1024;  // edge-scan blocks
  int* bsum = (int*)alloc((size_t)(NSB + 1) * 4);
  int* bsumE = (int*)alloc((size_t)(ESB + 1) * 4);
  // contiguous zero region: deg_i, cursor, rowsum, degf
  char* zero_base = wp;
  int* deg_i = (int*)alloc((size_t)N * 4);
  int* cursor = (int*)alloc((size_t)N * 4);
  float* rowsum = (float*)alloc((size_t)N * 4);
  float* degf = (float*)alloc((size_t)N * 4);
  size_t zero_bytes = (size_t)(wp - zero_base);

  float* out_h = (float*)d_out;            // [N,256]
  float* out_att = out_h + (size_t)N * HF; // [E]
  float* out_self = out_att + E;           // [N]

  const int NB4 = (N + 3) / 4;        // wave-per-node grids
  const int EBT = (E + 255) / 256;    // thread-per-edge grids
  const int NBT = (N + 255) / 256;
  const int EB8 = (E + 31) / 32;      // 8-lane-group-per-edge grid

  // ---- zero accumulators (ws/d_out are poisoned before every call) ----
  hipMemsetAsync(zero_base, 0, zero_bytes, stream);
  hipMemsetAsync(out_att, 0, (size_t)E * 4, stream);

  // ---- CSR by dst (u16 payload) ----
  hist_kernel<<<EBT, 256, 0, stream>>>(edst, deg_i, E);
  scanA_kernel<<<NSB, 1024, 0, stream>>>(deg_i, row_start, bsum, N);
  scanB_kernel<<<1, 1024, 0, stream>>>(bsum, NSB);
  scanC_kernel<<<(N + 256) / 256, 256, 0, stream>>>(row_start, bsum, N, NSB);
  scatter_kernel<<<EBT, 256, 0, stream>>>(esrc, edst, row_start, cursor,
                                          csr_src, E);

  // ---- weight packing for MFMA (tiny) ----
  wpack_kernel<<<(16 * 4 * 64 + 255) / 256, 256, 0, stream>>>(W0, Wf0, 128);
  wpack_kernel<<<(16 * 8 * 64 + 255) / 256, 256, 0, stream>>>(W1, Wf1, 256);

  // ---- att_coef #1 on x: bf16 cosine mask (edge order) + compaction ----
  xprep_kernel<<<NB4, 256, 0, stream>>>(x, xinv, xnb, x16, N);
  edge_mask8_kernel<<<EB8, 256, 0, stream>>>(xnb, x, xinv, esrc, edst, mask2,
                                             E);
  scanA_kernel<<<ESB, 1024, 0, stream>>>(mask2, pos2, bsumE, E);
  scanB_kernel<<<1, 1024, 0, stream>>>(bsumE, ESB);
  scanC_kernel<<<(E + 256) / 256, 256, 0, stream>>>(pos2, bsumE, E, ESB);
  compact_kernel<<<EBT, 256, 0, stream>>>(mask2, pos2, esrc, edst, cs, cd, ce,
                                          E);

  // ---- layer 0: feat16/el/er = MFMA gemm; aggregate -> h0 (+f16 copy) ----
  {
    dim3 g((N + 127) / 128, NH);
    gemm_mfma_kernel<<<g, 256, 0, stream>>>(x16, Wf0, a0, feat16, el, er, N,
                                            128);
  }
  gat_agg_kernel<<<NB4, 256, 0, stream>>>(feat16, el, er, row_start, csr_src,
                                          b0, h0, h0inv, h016, N, 1);

  // ---- att_coef #2 on h0 over survivors: att_w + self_w ----
  sim2_kernel<<<1024, 256, 0, stream>>>(h0, h0inv, cs, cd, pos2 + E, svc,
                                        rowsum, degf);
  att_w_kernel<<<512, 256, 0, stream>>>(svc, rowsum, cs, ce, pos2 + E,
                                        out_att);
  self_w_kernel<<<NBT, 256, 0, stream>>>(degf, out_self, N);

  // ---- layer 1: feat16/el/er = MFMA gemm; aggregate -> out_h ----
  {
    dim3 g((N + 127) / 128, NH);
    gemm_mfma_kernel<<<g, 256, 0, stream>>>(h016, Wf1, a1, feat16, el, er, N,
                                            256);
  }
  gat_agg_kernel<<<NB4, 256, 0, stream>>>(feat16, el, er, row_start, csr_src,
                                          b1, out_h, nullptr, nullptr, N, 0);
}